// Round 2
// baseline (1590.762 us; speedup 1.0000x reference)
//
#include <hip/hip_runtime.h>
#include <math.h>

#define NUSER 100000
#define NITEM 100000
#define NEDGE 800000
#define DIN 128
#define HD 256
#define BM 64
#define BK 64

typedef __attribute__((ext_vector_type(8))) short bf16x8;
typedef __attribute__((ext_vector_type(4))) float f32x4;

__device__ __forceinline__ float gelu_f(float x) {
    return 0.5f * x * (1.0f + erff(x * 0.70710678118654752440f));
}
__device__ __forceinline__ unsigned short f2bf(float f) {
    union { unsigned int i; float f; } v; v.f = f;
    unsigned int r = (v.i + 0x7FFFu + ((v.i >> 16) & 1u)) >> 16;  // RNE
    return (unsigned short)r;
}
__device__ __forceinline__ float bflo(unsigned int p) {
    union { unsigned int i; float f; } v; v.i = p << 16; return v.f;
}
__device__ __forceinline__ float bfhi(unsigned int p) {
    union { unsigned int i; float f; } v; v.i = p & 0xFFFF0000u; return v.f;
}

// ---------------- CSR build ----------------
// y=0: dst0 -> cnt0 ; y=1: dst1 -> cnt1
__global__ void k_hist2(const int* __restrict__ dst0, int* __restrict__ cnt0,
                        const int* __restrict__ dst1, int* __restrict__ cnt1, int n) {
    const int* dst = blockIdx.y ? dst1 : dst0;
    int* cnt = blockIdx.y ? cnt1 : cnt0;
    for (int i = blockIdx.x * blockDim.x + threadIdx.x; i < n; i += gridDim.x * blockDim.x)
        atomicAdd(&cnt[dst[i]], 1);
}

#define SCHUNK 8192
__global__ __launch_bounds__(1024) void k_scan_part(
    const int* __restrict__ cnt0, int* __restrict__ rp0, int n0, int nb0, int* __restrict__ csum0,
    const int* __restrict__ cnt1, int* __restrict__ rp1, int n1, int* __restrict__ csum1) {
    const int b = blockIdx.x;
    const int* cnt; int* rp; int n; int* csum; int chunk;
    if (b < nb0) { cnt = cnt0; rp = rp0; n = n0; csum = csum0; chunk = b; }
    else         { cnt = cnt1; rp = rp1; n = n1; csum = csum1; chunk = b - nb0; }
    const int t = threadIdx.x;
    const int lane = t & 63, wid = t >> 6;
    const int base = chunk * SCHUNK + t * 8;

    int v[8]; int s = 0;
    #pragma unroll
    for (int k = 0; k < 8; ++k) {
        int idx = base + k;
        int x = (idx < n) ? cnt[idx] : 0;
        v[k] = s; s += x;
    }
    int ws = s;
    #pragma unroll
    for (int off = 1; off < 64; off <<= 1) {
        int y = __shfl_up(ws, off, 64);
        if (lane >= off) ws += y;
    }
    __shared__ int wsum[16];
    if (lane == 63) wsum[wid] = ws;
    __syncthreads();
    int wexc = 0;
    for (int w = 0; w < wid; ++w) wexc += wsum[w];
    const int texc = wexc + (ws - s);
    #pragma unroll
    for (int k = 0; k < 8; ++k) {
        int idx = base + k;
        if (idx < n) rp[idx] = texc + v[k];
    }
    if (t == 1023) csum[chunk] = texc + s;
}

__global__ __launch_bounds__(1024) void k_scan_fin(
    int* __restrict__ rp0, int* __restrict__ cur0, int n0, int nb0, const int* __restrict__ csum0,
    int* __restrict__ rp1, int* __restrict__ cur1, int n1, int nb1, const int* __restrict__ csum1) {
    const int b = blockIdx.x;
    int* rp; int* cur; int n; const int* csum; int chunk; int nb;
    if (b < nb0) { rp = rp0; cur = cur0; n = n0; csum = csum0; chunk = b;       nb = nb0; }
    else         { rp = rp1; cur = cur1; n = n1; csum = csum1; chunk = b - nb0; nb = nb1; }
    int off = 0;
    for (int w = 0; w < chunk; ++w) off += csum[w];
    const int t = threadIdx.x;
    const int base = chunk * SCHUNK + t;
    #pragma unroll
    for (int k = 0; k < 8; ++k) {
        int idx = base + k * 1024;
        if (idx < n) { int x = rp[idx] + off; rp[idx] = x; cur[idx] = x; }
    }
    if (chunk == nb - 1 && t == 0) rp[n] = off + csum[nb - 1];
}

__global__ void k_scatter2(const int* __restrict__ s0, const int* __restrict__ d0,
                           int* __restrict__ c0, int* __restrict__ l0,
                           const int* __restrict__ s1, const int* __restrict__ d1,
                           int* __restrict__ c1, int* __restrict__ l1, int n) {
    const int* src = blockIdx.y ? s1 : s0;
    const int* dst = blockIdx.y ? d1 : d0;
    int* cur = blockIdx.y ? c1 : c0;
    int* sl  = blockIdx.y ? l1 : l0;
    for (int i = blockIdx.x * blockDim.x + threadIdx.x; i < n; i += gridDim.x * blockDim.x) {
        int p = atomicAdd(&cur[dst[i]], 1);
        sl[p] = src[i];
    }
}

// ---------------- weight prep: all 12 transposed conversions in ONE launch ----------------
struct CvtT12 {
    const float* src[12];
    unsigned short* dst[12];
    int K[12]; int Kt[12]; int koff[12];
};
__global__ void k_cvtT_all(CvtT12 J) {
    const int job = blockIdx.y;
    const float* src = J.src[job];
    unsigned short* dst = J.dst[job];
    const int K = J.K[job], Kt = J.Kt[job], koff = J.koff[job];
    for (int i = blockIdx.x * blockDim.x + threadIdx.x; i < K * 256; i += gridDim.x * blockDim.x) {
        int k = i >> 8, n = i & 255;
        dst[(size_t)n * Kt + koff + k] = f2bf(src[i]);
    }
}

// ---------------- input projection: f32 A (convert during staging) + GELU, bf16 out ----------------
// y selects user/item param set.
struct ProjArgs {
    const float* X; const unsigned short* WT; const float* bias;
    unsigned short* out; int M;
};
__global__ __launch_bounds__(256, 3) void k_proj(ProjArgs p0, ProjArgs p1) {
    ProjArgs P; if (blockIdx.y == 0) P = p0; else P = p1;
    const int Kt = DIN;
    __shared__ char sm[BM * 128 + 256 * 128];  // A 8KB + B 32KB
    char* sA = sm;
    char* sB = sm + BM * 128;
    const int t = threadIdx.x;
    const int wv = t >> 6, l = t & 63;
    const int l15 = l & 15, lq = l >> 4;
    const int r0 = blockIdx.x * BM;
    const int M = P.M;

    f32x4 acc[4][4];
    #pragma unroll
    for (int i = 0; i < 4; ++i)
        #pragma unroll
        for (int j = 0; j < 4; ++j) acc[i][j] = (f32x4){0, 0, 0, 0};

    #pragma unroll 1
    for (int c = 0; c < Kt / BK; ++c) {
        const int k0 = c * BK;
        __syncthreads();
        #pragma unroll
        for (int j = 0; j < 2; ++j) {  // A: 512 16B units, from f32 source
            int u = t + 256 * j;
            int r = u >> 3, sg = u & 7;
            int gr = r0 + r; if (gr >= M) gr = M - 1;
            const float* p = P.X + (size_t)gr * Kt + k0 + sg * 8;
            float4 f0 = *(const float4*)(p);
            float4 f1 = *(const float4*)(p + 4);
            uint4 v;
            v.x = (unsigned int)f2bf(f0.x) | ((unsigned int)f2bf(f0.y) << 16);
            v.y = (unsigned int)f2bf(f0.z) | ((unsigned int)f2bf(f0.w) << 16);
            v.z = (unsigned int)f2bf(f1.x) | ((unsigned int)f2bf(f1.y) << 16);
            v.w = (unsigned int)f2bf(f1.z) | ((unsigned int)f2bf(f1.w) << 16);
            *(uint4*)(sA + r * 128 + ((sg ^ (r & 7)) << 4)) = v;
        }
        #pragma unroll
        for (int j = 0; j < 8; ++j) {  // B: 2048 16B units
            int u = t + 256 * j;
            int n = u >> 3, sg = u & 7;
            uint4 v = *(const uint4*)(P.WT + (size_t)n * Kt + k0 + sg * 8);
            *(uint4*)(sB + n * 128 + ((sg ^ (n & 7)) << 4)) = v;
        }
        __syncthreads();
        #pragma unroll
        for (int ks = 0; ks < 2; ++ks) {
            bf16x8 af[4], bfr[4];
            int sg = ks * 4 + lq;
            #pragma unroll
            for (int mt = 0; mt < 4; ++mt) {
                int m = mt * 16 + l15;
                af[mt] = *(const bf16x8*)(sA + m * 128 + ((sg ^ (m & 7)) << 4));
            }
            #pragma unroll
            for (int nt = 0; nt < 4; ++nt) {
                int n = wv * 64 + nt * 16 + l15;
                bfr[nt] = *(const bf16x8*)(sB + n * 128 + ((sg ^ (n & 7)) << 4));
            }
            #pragma unroll
            for (int mt = 0; mt < 4; ++mt)
                #pragma unroll
                for (int nt = 0; nt < 4; ++nt)
                    acc[mt][nt] = __builtin_amdgcn_mfma_f32_16x16x32_bf16(
                        af[mt], bfr[nt], acc[mt][nt], 0, 0, 0);
        }
    }
    #pragma unroll
    for (int nt = 0; nt < 4; ++nt) {
        int col = wv * 64 + nt * 16 + l15;
        float bs = P.bias[col];
        #pragma unroll
        for (int mt = 0; mt < 4; ++mt) {
            int rowb = r0 + mt * 16 + lq * 4;
            #pragma unroll
            for (int rg = 0; rg < 4; ++rg) {
                int row = rowb + rg;
                if (row < M)
                    P.out[(size_t)row * HD + col] = f2bf(gelu_f(acc[mt][nt][rg] + bs));
            }
        }
    }
}

// ---------------- fused SAGE conv: LDS gather-mean + dual-A GEMM + GELU ----------------
// Per block: gather-mean 64 dst rows from h_src (CSR) into sAgg (32KB, swizzled),
// then C = GELU([sAgg | h_dst] @ WT + b). Chunks 0-3 read A from sAgg (no global agg
// buffer at all), chunks 4-7 stage h_dst rows into sA. y selects the relation.
// LDS 72KB -> 2 blocks/CU; gather of one block overlaps GEMM of the co-resident one.
struct ConvArgs {
    const unsigned short* h_src; const unsigned short* h_dst;
    const int* rp; const int* sl;
    const unsigned short* WT; const float* bias;
    unsigned short* out; int M;
};
__global__ __launch_bounds__(256, 2) void k_conv(ConvArgs a0, ConvArgs a1) {
    ConvArgs P; if (blockIdx.y == 0) P = a0; else P = a1;
    const int t = threadIdx.x;
    const int wv = t >> 6, l = t & 63;
    const int l15 = l & 15, lq = l >> 4;
    const int r0 = blockIdx.x * BM;
    const int M = P.M;

    __shared__ char sm[BM * 512 + BM * 128 + 256 * 128];  // sAgg 32K + sA 8K + sB 32K
    char* sAgg = sm;
    char* sA = sm + BM * 512;
    char* sB = sA + BM * 128;

    // ---- gather phase: wave wv owns local rows [wv*16, wv*16+16) ----
    #pragma unroll 1
    for (int i = 0; i < 16; ++i) {
        const int rloc = wv * 16 + i;
        int row = r0 + rloc; if (row >= M) row = M - 1;
        const int beg = P.rp[row], end = P.rp[row + 1];
        float a0 = 0, a1 = 0, a2 = 0, a3 = 0;
        int e = beg;
        #pragma unroll 1
        for (; e + 4 <= end; e += 4) {
            int s0 = P.sl[e], s1 = P.sl[e + 1], s2 = P.sl[e + 2], s3 = P.sl[e + 3];
            uint2 v0 = *(const uint2*)(P.h_src + (size_t)s0 * HD + 4 * l);
            uint2 v1 = *(const uint2*)(P.h_src + (size_t)s1 * HD + 4 * l);
            uint2 v2 = *(const uint2*)(P.h_src + (size_t)s2 * HD + 4 * l);
            uint2 v3 = *(const uint2*)(P.h_src + (size_t)s3 * HD + 4 * l);
            a0 += bflo(v0.x) + bflo(v1.x) + bflo(v2.x) + bflo(v3.x);
            a1 += bfhi(v0.x) + bfhi(v1.x) + bfhi(v2.x) + bfhi(v3.x);
            a2 += bflo(v0.y) + bflo(v1.y) + bflo(v2.y) + bflo(v3.y);
            a3 += bfhi(v0.y) + bfhi(v1.y) + bfhi(v2.y) + bfhi(v3.y);
        }
        #pragma unroll 1
        for (; e < end; ++e) {
            uint2 v = *(const uint2*)(P.h_src + (size_t)P.sl[e] * HD + 4 * l);
            a0 += bflo(v.x); a1 += bfhi(v.x); a2 += bflo(v.y); a3 += bfhi(v.y);
        }
        const float inv = 1.0f / fmaxf((float)(end - beg), 1.0f);
        unsigned int lo = (unsigned int)f2bf(a0 * inv) | ((unsigned int)f2bf(a1 * inv) << 16);
        unsigned int hi = (unsigned int)f2bf(a2 * inv) | ((unsigned int)f2bf(a3 * inv) << 16);
        uint2 o = {lo, hi};
        // lane l covers cols [4l,4l+4) = 8B; 16B unit s=l>>1, quarter q=s>>3, unit u=s&7
        const int s = l >> 1, q = s >> 3, u = s & 7;
        *(uint2*)(sAgg + rloc * 512 + q * 128 + ((u ^ (rloc & 7)) << 4) + (l & 1) * 8) = o;
    }

    f32x4 acc[4][4];
    #pragma unroll
    for (int i = 0; i < 4; ++i)
        #pragma unroll
        for (int j = 0; j < 4; ++j) acc[i][j] = (f32x4){0, 0, 0, 0};

    #pragma unroll 1
    for (int c = 0; c < 8; ++c) {
        const int k0 = c * BK;
        __syncthreads();  // WAR on sA/sB; also orders gather writes before c=0 reads
        if (c >= 4) {
            #pragma unroll
            for (int j = 0; j < 2; ++j) {  // A2 = h_dst rows
                int u = t + 256 * j;
                int r = u >> 3, sg = u & 7;
                int gr = r0 + r; if (gr >= M) gr = M - 1;
                uint4 v = *(const uint4*)(P.h_dst + (size_t)gr * HD + (k0 - HD) + sg * 8);
                *(uint4*)(sA + r * 128 + ((sg ^ (r & 7)) << 4)) = v;
            }
        }
        #pragma unroll
        for (int j = 0; j < 8; ++j) {  // B: WT is [256][512]
            int u = t + 256 * j;
            int n = u >> 3, sg = u & 7;
            uint4 v = *(const uint4*)(P.WT + (size_t)n * 512 + k0 + sg * 8);
            *(uint4*)(sB + n * 128 + ((sg ^ (n & 7)) << 4)) = v;
        }
        __syncthreads();
        #pragma unroll
        for (int ks = 0; ks < 2; ++ks) {
            bf16x8 af[4], bfr[4];
            int sg = ks * 4 + lq;
            #pragma unroll
            for (int mt = 0; mt < 4; ++mt) {
                int m = mt * 16 + l15;
                af[mt] = (c < 4)
                    ? *(const bf16x8*)(sAgg + m * 512 + c * 128 + ((sg ^ (m & 7)) << 4))
                    : *(const bf16x8*)(sA + m * 128 + ((sg ^ (m & 7)) << 4));
            }
            #pragma unroll
            for (int nt = 0; nt < 4; ++nt) {
                int n = wv * 64 + nt * 16 + l15;
                bfr[nt] = *(const bf16x8*)(sB + n * 128 + ((sg ^ (n & 7)) << 4));
            }
            #pragma unroll
            for (int mt = 0; mt < 4; ++mt)
                #pragma unroll
                for (int nt = 0; nt < 4; ++nt)
                    acc[mt][nt] = __builtin_amdgcn_mfma_f32_16x16x32_bf16(
                        af[mt], bfr[nt], acc[mt][nt], 0, 0, 0);
        }
    }
    #pragma unroll
    for (int nt = 0; nt < 4; ++nt) {
        int col = wv * 64 + nt * 16 + l15;
        float bs = P.bias[col];
        #pragma unroll
        for (int mt = 0; mt < 4; ++mt) {
            int rowb = r0 + mt * 16 + lq * 4;
            #pragma unroll
            for (int rg = 0; rg < 4; ++rg) {
                int row = rowb + rg;
                if (row < M)
                    P.out[(size_t)row * HD + col] = f2bf(gelu_f(acc[mt][nt][rg] + bs));
            }
        }
    }
}

// ---------------- head GEMM + LayerNorm epilogue, f32 out ----------------
struct LnArgs {
    const unsigned short* A; const unsigned short* WT; const float* bias;
    const float* g; const float* b2; float* out; int M;
};
__global__ __launch_bounds__(256, 3) void k_ln(LnArgs g0, LnArgs g1) {
    LnArgs P; if (blockIdx.y == 0) P = g0; else P = g1;
    const int Kt = HD;
    __shared__ char sm[BM * 128 + 256 * 128];
    char* sA = sm;
    char* sB = sm + BM * 128;
    const int t = threadIdx.x;
    const int wv = t >> 6, l = t & 63;
    const int l15 = l & 15, lq = l >> 4;
    const int r0 = blockIdx.x * BM;
    const int M = P.M;

    f32x4 acc[16];
    #pragma unroll
    for (int i = 0; i < 16; ++i) acc[i] = (f32x4){0, 0, 0, 0};

    #pragma unroll 1
    for (int c = 0; c < Kt / BK; ++c) {
        const int k0 = c * BK;
        __syncthreads();
        #pragma unroll
        for (int j = 0; j < 2; ++j) {
            int u = t + 256 * j;
            int r = u >> 3, sg = u & 7;
            int gr = r0 + r; if (gr >= M) gr = M - 1;
            uint4 v = *(const uint4*)(P.A + (size_t)gr * Kt + k0 + sg * 8);
            *(uint4*)(sA + r * 128 + ((sg ^ (r & 7)) << 4)) = v;
        }
        #pragma unroll
        for (int j = 0; j < 8; ++j) {
            int u = t + 256 * j;
            int n = u >> 3, sg = u & 7;
            uint4 v = *(const uint4*)(P.WT + (size_t)n * Kt + k0 + sg * 8);
            *(uint4*)(sB + n * 128 + ((sg ^ (n & 7)) << 4)) = v;
        }
        __syncthreads();
        #pragma unroll
        for (int ks = 0; ks < 2; ++ks) {
            int sg = ks * 4 + lq;
            int m = wv * 16 + l15;
            bf16x8 af = *(const bf16x8*)(sA + m * 128 + ((sg ^ (m & 7)) << 4));
            #pragma unroll
            for (int nt = 0; nt < 16; ++nt) {
                int n = nt * 16 + l15;
                bf16x8 bfr = *(const bf16x8*)(sB + n * 128 + ((sg ^ (n & 7)) << 4));
                acc[nt] = __builtin_amdgcn_mfma_f32_16x16x32_bf16(af, bfr, acc[nt], 0, 0, 0);
            }
        }
    }
    #pragma unroll
    for (int nt = 0; nt < 16; ++nt) {
        float bs = P.bias[nt * 16 + l15];
        #pragma unroll
        for (int rg = 0; rg < 4; ++rg) acc[nt][rg] += bs;
    }
    float s0 = 0, s1 = 0, s2 = 0, s3 = 0;
    #pragma unroll
    for (int nt = 0; nt < 16; ++nt) { s0 += acc[nt][0]; s1 += acc[nt][1]; s2 += acc[nt][2]; s3 += acc[nt][3]; }
    #pragma unroll
    for (int off = 1; off < 16; off <<= 1) {
        s0 += __shfl_xor(s0, off, 64); s1 += __shfl_xor(s1, off, 64);
        s2 += __shfl_xor(s2, off, 64); s3 += __shfl_xor(s3, off, 64);
    }
    const float mu0 = s0 * (1.0f / HD), mu1 = s1 * (1.0f / HD),
                mu2 = s2 * (1.0f / HD), mu3 = s3 * (1.0f / HD);
    float q0 = 0, q1 = 0, q2 = 0, q3 = 0;
    #pragma unroll
    for (int nt = 0; nt < 16; ++nt) {
        float d0 = acc[nt][0] - mu0, d1 = acc[nt][1] - mu1,
              d2 = acc[nt][2] - mu2, d3 = acc[nt][3] - mu3;
        q0 += d0 * d0; q1 += d1 * d1; q2 += d2 * d2; q3 += d3 * d3;
    }
    #pragma unroll
    for (int off = 1; off < 16; off <<= 1) {
        q0 += __shfl_xor(q0, off, 64); q1 += __shfl_xor(q1, off, 64);
        q2 += __shfl_xor(q2, off, 64); q3 += __shfl_xor(q3, off, 64);
    }
    const float rs0 = rsqrtf(q0 * (1.0f / HD) + 1e-5f), rs1 = rsqrtf(q1 * (1.0f / HD) + 1e-5f),
                rs2 = rsqrtf(q2 * (1.0f / HD) + 1e-5f), rs3 = rsqrtf(q3 * (1.0f / HD) + 1e-5f);
    const int rowb = r0 + wv * 16 + lq * 4;
    #pragma unroll
    for (int nt = 0; nt < 16; ++nt) {
        int col = nt * 16 + l15;
        float gg = P.g[col], bb = P.b2[col];
        float mu[4] = {mu0, mu1, mu2, mu3};
        float rs[4] = {rs0, rs1, rs2, rs3};
        #pragma unroll
        for (int rg = 0; rg < 4; ++rg) {
            int row = rowb + rg;
            if (row < M)
                P.out[(size_t)row * HD + col] = (acc[nt][rg] - mu[rg]) * rs[rg] * gg + bb;
        }
    }
}

extern "C" void kernel_launch(void* const* d_in, const int* in_sizes, int n_in,
                              void* d_out, int out_size, void* d_ws, size_t ws_size,
                              hipStream_t stream) {
    const float* x_user     = (const float*)d_in[0];
    const float* x_item     = (const float*)d_in[1];
    const int*   ei_ui_src  = (const int*)d_in[2];
    const int*   ei_ui_dst  = (const int*)d_in[3];
    const int*   ei_iu_src  = (const int*)d_in[4];
    const int*   ei_iu_dst  = (const int*)d_in[5];
    const float* lin_user_W = (const float*)d_in[6];
    const float* lin_user_b = (const float*)d_in[7];
    const float* lin_item_W = (const float*)d_in[8];
    const float* lin_item_b = (const float*)d_in[9];
    const float* c0_ui_Wl = (const float*)d_in[10];
    const float* c0_ui_bl = (const float*)d_in[11];
    const float* c0_ui_Wr = (const float*)d_in[12];
    const float* c0_iu_Wl = (const float*)d_in[13];
    const float* c0_iu_bl = (const float*)d_in[14];
    const float* c0_iu_Wr = (const float*)d_in[15];
    const float* c1_ui_Wl = (const float*)d_in[16];
    const float* c1_ui_bl = (const float*)d_in[17];
    const float* c1_ui_Wr = (const float*)d_in[18];
    const float* c1_iu_Wl = (const float*)d_in[19];
    const float* c1_iu_bl = (const float*)d_in[20];
    const float* c1_iu_Wr = (const float*)d_in[21];
    const float* out_user_W = (const float*)d_in[22];
    const float* out_user_b = (const float*)d_in[23];
    const float* out_item_W = (const float*)d_in[24];
    const float* out_item_b = (const float*)d_in[25];
    const float* ln_user_g  = (const float*)d_in[26];
    const float* ln_user_b2 = (const float*)d_in[27];
    const float* ln_item_g  = (const float*)d_in[28];
    const float* ln_item_b2 = (const float*)d_in[29];

    char* ws = (char*)d_ws;
    size_t off = 0;
    auto alloc = [&](size_t bytes) -> void* {
        void* p = ws + off;
        off += (bytes + 255) & ~(size_t)255;
        return p;
    };
    typedef unsigned short u16;
    u16* hu_a = (u16*)alloc((size_t)NUSER * HD * 2);
    u16* hi_a = (u16*)alloc((size_t)NITEM * HD * 2);
    u16* WT_lu   = (u16*)alloc((size_t)HD * DIN * 2);
    u16* WT_li   = (u16*)alloc((size_t)HD * DIN * 2);
    u16* WT_c0ui = (u16*)alloc((size_t)HD * 2 * HD * 2);
    u16* WT_c0iu = (u16*)alloc((size_t)HD * 2 * HD * 2);
    u16* WT_c1ui = (u16*)alloc((size_t)HD * 2 * HD * 2);
    u16* WT_c1iu = (u16*)alloc((size_t)HD * 2 * HD * 2);
    u16* WT_ou   = (u16*)alloc((size_t)HD * HD * 2);
    u16* WT_oi   = (u16*)alloc((size_t)HD * HD * 2);
    int* rp_i  = (int*)alloc((NITEM + 1) * 4);
    int* rp_u  = (int*)alloc((NUSER + 1) * 4);
    int* cur_i = (int*)alloc(NITEM * 4);
    int* cur_u = (int*)alloc(NUSER * 4);
    int* cnt_i = (int*)alloc(NITEM * 4);
    int* cnt_u = (int*)alloc(NUSER * 4);
    int* sl_ui = (int*)alloc((size_t)NEDGE * 4);
    int* sl_iu = (int*)alloc((size_t)NEDGE * 4);
    int* csum_i = (int*)alloc(64 * 4);
    int* csum_u = (int*)alloc(64 * 4);

    // h pong buffers (bf16) live in d_out's 204.8MB; heads overwrite d_out last
    u16* hu_b = (u16*)d_out;
    u16* hi_b = (u16*)d_out + (size_t)NUSER * HD;

    const int MMG = (NUSER + BM - 1) / BM;
    const int NBI = (NITEM + SCHUNK - 1) / SCHUNK;
    const int NBU = (NUSER + SCHUNK - 1) / SCHUNK;

    // ---- CSR build ----
    hipMemsetAsync(cnt_i, 0, NITEM * 4, stream);
    hipMemsetAsync(cnt_u, 0, NUSER * 4, stream);
    k_hist2<<<dim3(1024, 2), 256, 0, stream>>>(ei_ui_dst, cnt_i, ei_iu_dst, cnt_u, NEDGE);
    k_scan_part<<<NBI + NBU, 1024, 0, stream>>>(cnt_i, rp_i, NITEM, NBI, csum_i,
                                                cnt_u, rp_u, NUSER, csum_u);
    k_scan_fin<<<NBI + NBU, 1024, 0, stream>>>(rp_i, cur_i, NITEM, NBI, csum_i,
                                               rp_u, cur_u, NUSER, NBU, csum_u);
    k_scatter2<<<dim3(1024, 2), 256, 0, stream>>>(ei_ui_src, ei_ui_dst, cur_i, sl_ui,
                                                  ei_iu_src, ei_iu_dst, cur_u, sl_iu, NEDGE);

    // ---- weight prep (single launch, 12 jobs) ----
    CvtT12 J;
    const float* srcs[12] = {lin_user_W, lin_item_W,
                             c0_ui_Wl, c0_ui_Wr, c0_iu_Wl, c0_iu_Wr,
                             c1_ui_Wl, c1_ui_Wr, c1_iu_Wl, c1_iu_Wr,
                             out_user_W, out_item_W};
    u16* dsts[12] = {WT_lu, WT_li, WT_c0ui, WT_c0ui, WT_c0iu, WT_c0iu,
                     WT_c1ui, WT_c1ui, WT_c1iu, WT_c1iu, WT_ou, WT_oi};
    int Ks[12]    = {DIN, DIN, HD, HD, HD, HD, HD, HD, HD, HD, HD, HD};
    int Kts[12]   = {DIN, DIN, 2*HD, 2*HD, 2*HD, 2*HD, 2*HD, 2*HD, 2*HD, 2*HD, HD, HD};
    int koffs[12] = {0, 0, 0, HD, 0, HD, 0, HD, 0, HD, 0, 0};
    for (int i = 0; i < 12; ++i) {
        J.src[i] = srcs[i]; J.dst[i] = dsts[i];
        J.K[i] = Ks[i]; J.Kt[i] = Kts[i]; J.koff[i] = koffs[i];
    }
    k_cvtT_all<<<dim3(128, 12), 256, 0, stream>>>(J);

    // ---- input projections (f32 A, one launch) ----
    ProjArgs pu = {x_user, WT_lu, lin_user_b, hu_a, NUSER};
    ProjArgs pi = {x_item, WT_li, lin_item_b, hi_a, NITEM};
    k_proj<<<dim3(MMG, 2), 256, 0, stream>>>(pu, pi);

    // ---- layer 0 (both relations in one launch, gather fused in LDS) ----
    ConvArgs l0ui = {hu_a, hi_a, rp_i, sl_ui, WT_c0ui, c0_ui_bl, hi_b, NITEM};
    ConvArgs l0iu = {hi_a, hu_a, rp_u, sl_iu, WT_c0iu, c0_iu_bl, hu_b, NUSER};
    k_conv<<<dim3(MMG, 2), 256, 0, stream>>>(l0ui, l0iu);

    // ---- layer 1 ----
    ConvArgs l1ui = {hu_b, hi_b, rp_i, sl_ui, WT_c1ui, c1_ui_bl, hi_a, NITEM};
    ConvArgs l1iu = {hi_b, hu_b, rp_u, sl_iu, WT_c1iu, c1_iu_bl, hu_a, NUSER};
    k_conv<<<dim3(MMG, 2), 256, 0, stream>>>(l1ui, l1iu);

    // ---- heads + LayerNorm (one launch, read ws, write d_out) ----
    LnArgs hu = {hu_a, WT_ou, out_user_b, ln_user_g, ln_user_b2, (float*)d_out, NUSER};
    LnArgs hi = {hi_a, WT_oi, out_item_b, ln_item_g, ln_item_b2,
                 (float*)d_out + (size_t)NUSER * HD, NITEM};
    k_ln<<<dim3(MMG, 2), 256, 0, stream>>>(hu, hi);
}

// Round 4
// 1424.006 us; speedup vs baseline: 1.1171x; 1.1171x over previous
//
#include <hip/hip_runtime.h>
#include <math.h>

#define NUSER 100000
#define NITEM 100000
#define NEDGE 800000
#define DIN 128
#define HD 256
#define BM 64
#define BK 64

typedef __attribute__((ext_vector_type(8))) short bf16x8;
typedef __attribute__((ext_vector_type(4))) float f32x4;

__device__ __forceinline__ float gelu_f(float x) {
    return 0.5f * x * (1.0f + erff(x * 0.70710678118654752440f));
}
__device__ __forceinline__ unsigned short f2bf(float f) {
    union { unsigned int i; float f; } v; v.f = f;
    unsigned int r = (v.i + 0x7FFFu + ((v.i >> 16) & 1u)) >> 16;  // RNE
    return (unsigned short)r;
}
__device__ __forceinline__ float bflo(unsigned int p) {
    union { unsigned int i; float f; } v; v.i = p << 16; return v.f;
}
__device__ __forceinline__ float bfhi(unsigned int p) {
    union { unsigned int i; float f; } v; v.i = p & 0xFFFF0000u; return v.f;
}

// ---------------- CSR build ----------------
__global__ void k_hist2(const int* __restrict__ dst0, int* __restrict__ cnt0,
                        const int* __restrict__ dst1, int* __restrict__ cnt1, int n) {
    const int* dst = blockIdx.y ? dst1 : dst0;
    int* cnt = blockIdx.y ? cnt1 : cnt0;
    for (int i = blockIdx.x * blockDim.x + threadIdx.x; i < n; i += gridDim.x * blockDim.x)
        atomicAdd(&cnt[dst[i]], 1);
}

#define SCHUNK 8192
__global__ __launch_bounds__(1024) void k_scan_part(
    const int* __restrict__ cnt0, int* __restrict__ rp0, int n0, int nb0, int* __restrict__ csum0,
    const int* __restrict__ cnt1, int* __restrict__ rp1, int n1, int* __restrict__ csum1) {
    const int b = blockIdx.x;
    const int* cnt; int* rp; int n; int* csum; int chunk;
    if (b < nb0) { cnt = cnt0; rp = rp0; n = n0; csum = csum0; chunk = b; }
    else         { cnt = cnt1; rp = rp1; n = n1; csum = csum1; chunk = b - nb0; }
    const int t = threadIdx.x;
    const int lane = t & 63, wid = t >> 6;
    const int base = chunk * SCHUNK + t * 8;

    int v[8]; int s = 0;
    #pragma unroll
    for (int k = 0; k < 8; ++k) {
        int idx = base + k;
        int x = (idx < n) ? cnt[idx] : 0;
        v[k] = s; s += x;
    }
    int ws = s;
    #pragma unroll
    for (int off = 1; off < 64; off <<= 1) {
        int y = __shfl_up(ws, off, 64);
        if (lane >= off) ws += y;
    }
    __shared__ int wsum[16];
    if (lane == 63) wsum[wid] = ws;
    __syncthreads();
    int wexc = 0;
    for (int w = 0; w < wid; ++w) wexc += wsum[w];
    const int texc = wexc + (ws - s);
    #pragma unroll
    for (int k = 0; k < 8; ++k) {
        int idx = base + k;
        if (idx < n) rp[idx] = texc + v[k];
    }
    if (t == 1023) csum[chunk] = texc + s;
}

__global__ __launch_bounds__(1024) void k_scan_fin(
    int* __restrict__ rp0, int* __restrict__ cur0, int n0, int nb0, const int* __restrict__ csum0,
    int* __restrict__ rp1, int* __restrict__ cur1, int n1, int nb1, const int* __restrict__ csum1) {
    const int b = blockIdx.x;
    int* rp; int* cur; int n; const int* csum; int chunk; int nb;
    if (b < nb0) { rp = rp0; cur = cur0; n = n0; csum = csum0; chunk = b;       nb = nb0; }
    else         { rp = rp1; cur = cur1; n = n1; csum = csum1; chunk = b - nb0; nb = nb1; }
    int off = 0;
    for (int w = 0; w < chunk; ++w) off += csum[w];
    const int t = threadIdx.x;
    const int base = chunk * SCHUNK + t;
    #pragma unroll
    for (int k = 0; k < 8; ++k) {
        int idx = base + k * 1024;
        if (idx < n) { int x = rp[idx] + off; rp[idx] = x; cur[idx] = x; }
    }
    if (chunk == nb - 1 && t == 0) rp[n] = off + csum[nb - 1];
}

__global__ void k_scatter2(const int* __restrict__ s0, const int* __restrict__ d0,
                           int* __restrict__ c0, int* __restrict__ l0,
                           const int* __restrict__ s1, const int* __restrict__ d1,
                           int* __restrict__ c1, int* __restrict__ l1, int n) {
    const int* src = blockIdx.y ? s1 : s0;
    const int* dst = blockIdx.y ? d1 : d0;
    int* cur = blockIdx.y ? c1 : c0;
    int* sl  = blockIdx.y ? l1 : l0;
    for (int i = blockIdx.x * blockDim.x + threadIdx.x; i < n; i += gridDim.x * blockDim.x) {
        int p = atomicAdd(&cur[dst[i]], 1);
        sl[p] = src[i];
    }
}

// ---------------- weight prep: all 12 transposed conversions in ONE launch ----------------
struct CvtT12 {
    const float* src[12];
    unsigned short* dst[12];
    int K[12]; int Kt[12]; int koff[12];
};
__global__ void k_cvtT_all(CvtT12 J) {
    const int job = blockIdx.y;
    const float* src = J.src[job];
    unsigned short* dst = J.dst[job];
    const int K = J.K[job], Kt = J.Kt[job], koff = J.koff[job];
    for (int i = blockIdx.x * blockDim.x + threadIdx.x; i < K * 256; i += gridDim.x * blockDim.x) {
        int k = i >> 8, n = i & 255;
        dst[(size_t)n * Kt + koff + k] = f2bf(src[i]);
    }
}

// ---------------- input projection: f32 A (convert during staging) + GELU, bf16 out ----------------
struct ProjArgs {
    const float* X; const unsigned short* WT; const float* bias;
    unsigned short* out; int M;
};
__global__ __launch_bounds__(256, 3) void k_proj(ProjArgs p0, ProjArgs p1) {
    ProjArgs P; if (blockIdx.y == 0) P = p0; else P = p1;
    const int Kt = DIN;
    __shared__ char sm[BM * 128 + 256 * 128];  // A 8KB + B 32KB
    char* sA = sm;
    char* sB = sm + BM * 128;
    const int t = threadIdx.x;
    const int wv = t >> 6, l = t & 63;
    const int l15 = l & 15, lq = l >> 4;
    const int r0 = blockIdx.x * BM;
    const int M = P.M;

    f32x4 acc[4][4];
    #pragma unroll
    for (int i = 0; i < 4; ++i)
        #pragma unroll
        for (int j = 0; j < 4; ++j) acc[i][j] = (f32x4){0, 0, 0, 0};

    #pragma unroll 1
    for (int c = 0; c < Kt / BK; ++c) {
        const int k0 = c * BK;
        __syncthreads();
        #pragma unroll
        for (int j = 0; j < 2; ++j) {  // A: 512 16B units, from f32 source
            int u = t + 256 * j;
            int r = u >> 3, sg = u & 7;
            int gr = r0 + r; if (gr >= M) gr = M - 1;
            const float* p = P.X + (size_t)gr * Kt + k0 + sg * 8;
            float4 f0 = *(const float4*)(p);
            float4 f1 = *(const float4*)(p + 4);
            uint4 v;
            v.x = (unsigned int)f2bf(f0.x) | ((unsigned int)f2bf(f0.y) << 16);
            v.y = (unsigned int)f2bf(f0.z) | ((unsigned int)f2bf(f0.w) << 16);
            v.z = (unsigned int)f2bf(f1.x) | ((unsigned int)f2bf(f1.y) << 16);
            v.w = (unsigned int)f2bf(f1.z) | ((unsigned int)f2bf(f1.w) << 16);
            *(uint4*)(sA + r * 128 + ((sg ^ (r & 7)) << 4)) = v;
        }
        #pragma unroll
        for (int j = 0; j < 8; ++j) {  // B: 2048 16B units
            int u = t + 256 * j;
            int n = u >> 3, sg = u & 7;
            uint4 v = *(const uint4*)(P.WT + (size_t)n * Kt + k0 + sg * 8);
            *(uint4*)(sB + n * 128 + ((sg ^ (n & 7)) << 4)) = v;
        }
        __syncthreads();
        #pragma unroll
        for (int ks = 0; ks < 2; ++ks) {
            bf16x8 af[4], bfr[4];
            int sg = ks * 4 + lq;
            #pragma unroll
            for (int mt = 0; mt < 4; ++mt) {
                int m = mt * 16 + l15;
                af[mt] = *(const bf16x8*)(sA + m * 128 + ((sg ^ (m & 7)) << 4));
            }
            #pragma unroll
            for (int nt = 0; nt < 4; ++nt) {
                int n = wv * 64 + nt * 16 + l15;
                bfr[nt] = *(const bf16x8*)(sB + n * 128 + ((sg ^ (n & 7)) << 4));
            }
            #pragma unroll
            for (int mt = 0; mt < 4; ++mt)
                #pragma unroll
                for (int nt = 0; nt < 4; ++nt)
                    acc[mt][nt] = __builtin_amdgcn_mfma_f32_16x16x32_bf16(
                        af[mt], bfr[nt], acc[mt][nt], 0, 0, 0);
        }
    }
    #pragma unroll
    for (int nt = 0; nt < 4; ++nt) {
        int col = wv * 64 + nt * 16 + l15;
        float bs = P.bias[col];
        #pragma unroll
        for (int mt = 0; mt < 4; ++mt) {
            int rowb = r0 + mt * 16 + lq * 4;
            #pragma unroll
            for (int rg = 0; rg < 4; ++rg) {
                int row = rowb + rg;
                if (row < M)
                    P.out[(size_t)row * HD + col] = f2bf(gelu_f(acc[mt][nt][rg] + bs));
            }
        }
    }
}

// ---------------- fused SAGE conv v2 ----------------
// Per block: gather-mean 64 dst rows into sAgg (32KB LDS, swizzled; 8 edge-loads
// in flight per wave), then GEMM with A from {sAgg | h_dst-direct} and B (WT)
// read DIRECTLY from global (L2-resident, 16 rows x 64B per wave-load).
// LDS = 32KB only -> 4 blocks/CU (VGPR<=128); ONE barrier total, none in K-loop.
struct ConvArgs {
    const unsigned short* h_src; const unsigned short* h_dst;
    const int* rp; const int* sl;
    const unsigned short* WT; const float* bias;
    unsigned short* out; int M;
};
__global__ __launch_bounds__(256, 4) void k_conv(ConvArgs a0, ConvArgs a1) {
    ConvArgs P; if (blockIdx.y == 0) P = a0; else P = a1;
    const int t = threadIdx.x;
    const int wv = t >> 6, l = t & 63;
    const int l15 = l & 15, lq = l >> 4;
    const int r0 = blockIdx.x * BM;
    const int M = P.M;

    __shared__ char sAgg[BM * 512];  // 32KB

    // ---- gather phase: wave wv owns local rows [wv*16, wv*16+16), 8-deep ILP ----
    #pragma unroll 1
    for (int i = 0; i < 16; ++i) {
        const int rloc = wv * 16 + i;
        int row = r0 + rloc; if (row >= M) row = M - 1;
        const int beg = P.rp[row], end = P.rp[row + 1];
        float a0 = 0, a1 = 0, a2 = 0, a3 = 0;
        int e = beg;
        #pragma unroll 1
        for (; e + 8 <= end; e += 8) {
            uint2 v0 = *(const uint2*)(P.h_src + (size_t)P.sl[e + 0] * HD + 4 * l);
            uint2 v1 = *(const uint2*)(P.h_src + (size_t)P.sl[e + 1] * HD + 4 * l);
            uint2 v2 = *(const uint2*)(P.h_src + (size_t)P.sl[e + 2] * HD + 4 * l);
            uint2 v3 = *(const uint2*)(P.h_src + (size_t)P.sl[e + 3] * HD + 4 * l);
            uint2 v4 = *(const uint2*)(P.h_src + (size_t)P.sl[e + 4] * HD + 4 * l);
            uint2 v5 = *(const uint2*)(P.h_src + (size_t)P.sl[e + 5] * HD + 4 * l);
            uint2 v6 = *(const uint2*)(P.h_src + (size_t)P.sl[e + 6] * HD + 4 * l);
            uint2 v7 = *(const uint2*)(P.h_src + (size_t)P.sl[e + 7] * HD + 4 * l);
            a0 += bflo(v0.x) + bflo(v1.x) + bflo(v2.x) + bflo(v3.x)
                + bflo(v4.x) + bflo(v5.x) + bflo(v6.x) + bflo(v7.x);
            a1 += bfhi(v0.x) + bfhi(v1.x) + bfhi(v2.x) + bfhi(v3.x)
                + bfhi(v4.x) + bfhi(v5.x) + bfhi(v6.x) + bfhi(v7.x);
            a2 += bflo(v0.y) + bflo(v1.y) + bflo(v2.y) + bflo(v3.y)
                + bflo(v4.y) + bflo(v5.y) + bflo(v6.y) + bflo(v7.y);
            a3 += bfhi(v0.y) + bfhi(v1.y) + bfhi(v2.y) + bfhi(v3.y)
                + bfhi(v4.y) + bfhi(v5.y) + bfhi(v6.y) + bfhi(v7.y);
        }
        #pragma unroll 1
        for (; e + 4 <= end; e += 4) {
            uint2 v0 = *(const uint2*)(P.h_src + (size_t)P.sl[e + 0] * HD + 4 * l);
            uint2 v1 = *(const uint2*)(P.h_src + (size_t)P.sl[e + 1] * HD + 4 * l);
            uint2 v2 = *(const uint2*)(P.h_src + (size_t)P.sl[e + 2] * HD + 4 * l);
            uint2 v3 = *(const uint2*)(P.h_src + (size_t)P.sl[e + 3] * HD + 4 * l);
            a0 += bflo(v0.x) + bflo(v1.x) + bflo(v2.x) + bflo(v3.x);
            a1 += bfhi(v0.x) + bfhi(v1.x) + bfhi(v2.x) + bfhi(v3.x);
            a2 += bflo(v0.y) + bflo(v1.y) + bflo(v2.y) + bflo(v3.y);
            a3 += bfhi(v0.y) + bfhi(v1.y) + bfhi(v2.y) + bfhi(v3.y);
        }
        #pragma unroll 1
        for (; e < end; ++e) {
            uint2 v = *(const uint2*)(P.h_src + (size_t)P.sl[e] * HD + 4 * l);
            a0 += bflo(v.x); a1 += bfhi(v.x); a2 += bflo(v.y); a3 += bfhi(v.y);
        }
        const float inv = 1.0f / fmaxf((float)(end - beg), 1.0f);
        unsigned int lo = (unsigned int)f2bf(a0 * inv) | ((unsigned int)f2bf(a1 * inv) << 16);
        unsigned int hi = (unsigned int)f2bf(a2 * inv) | ((unsigned int)f2bf(a3 * inv) << 16);
        uint2 o = {lo, hi};
        const int s = l >> 1, q = s >> 3, u = s & 7;
        *(uint2*)(sAgg + rloc * 512 + q * 128 + ((u ^ (rloc & 7)) << 4) + (l & 1) * 8) = o;
    }
    __syncthreads();  // the ONLY barrier: gather writes visible to all waves

    f32x4 acc[4][4];
    #pragma unroll
    for (int i = 0; i < 4; ++i)
        #pragma unroll
        for (int j = 0; j < 4; ++j) acc[i][j] = (f32x4){0, 0, 0, 0};

    // per-lane B base: row band wv*64 + l15, WT stride 512
    const unsigned short* wt_lane = P.WT + (size_t)(wv * 64 + l15) * 512;
    // per-lane A rows for the dst half (clamped)
    size_t rb[4];
    #pragma unroll
    for (int mt = 0; mt < 4; ++mt) {
        int row = r0 + mt * 16 + l15; if (row >= M) row = M - 1;
        rb[mt] = (size_t)row * HD;
    }

    // chunks 0-3: A from sAgg (LDS), B direct from global
    #pragma unroll 1
    for (int c = 0; c < 4; ++c) {
        const int k0 = c * BK;
        #pragma unroll
        for (int ks = 0; ks < 2; ++ks) {
            const int sg = ks * 4 + lq;
            bf16x8 af[4], bfr[4];
            #pragma unroll
            for (int mt = 0; mt < 4; ++mt) {
                int m = mt * 16 + l15;
                af[mt] = *(const bf16x8*)(sAgg + m * 512 + c * 128 + ((sg ^ (m & 7)) << 4));
            }
            #pragma unroll
            for (int nt = 0; nt < 4; ++nt)
                bfr[nt] = *(const bf16x8*)(wt_lane + (size_t)nt * 16 * 512 + k0 + sg * 8);
            #pragma unroll
            for (int mt = 0; mt < 4; ++mt)
                #pragma unroll
                for (int nt = 0; nt < 4; ++nt)
                    acc[mt][nt] = __builtin_amdgcn_mfma_f32_16x16x32_bf16(
                        af[mt], bfr[nt], acc[mt][nt], 0, 0, 0);
        }
    }
    // chunks 4-7: A direct from h_dst global, B direct from global
    #pragma unroll 1
    for (int c = 0; c < 4; ++c) {
        const int k0 = (c + 4) * BK;
        #pragma unroll
        for (int ks = 0; ks < 2; ++ks) {
            const int sg = ks * 4 + lq;
            bf16x8 af[4], bfr[4];
            #pragma unroll
            for (int mt = 0; mt < 4; ++mt)
                af[mt] = *(const bf16x8*)(P.h_dst + rb[mt] + c * 64 + sg * 8);
            #pragma unroll
            for (int nt = 0; nt < 4; ++nt)
                bfr[nt] = *(const bf16x8*)(wt_lane + (size_t)nt * 16 * 512 + k0 + sg * 8);
            #pragma unroll
            for (int mt = 0; mt < 4; ++mt)
                #pragma unroll
                for (int nt = 0; nt < 4; ++nt)
                    acc[mt][nt] = __builtin_amdgcn_mfma_f32_16x16x32_bf16(
                        af[mt], bfr[nt], acc[mt][nt], 0, 0, 0);
        }
    }
    #pragma unroll
    for (int nt = 0; nt < 4; ++nt) {
        int col = wv * 64 + nt * 16 + l15;
        float bs = P.bias[col];
        #pragma unroll
        for (int mt = 0; mt < 4; ++mt) {
            int rowb = r0 + mt * 16 + lq * 4;
            #pragma unroll
            for (int rg = 0; rg < 4; ++rg) {
                int row = rowb + rg;
                if (row < M)
                    P.out[(size_t)row * HD + col] = f2bf(gelu_f(acc[mt][nt][rg] + bs));
            }
        }
    }
}

// ---------------- head GEMM + LayerNorm epilogue, f32 out ----------------
struct LnArgs {
    const unsigned short* A; const unsigned short* WT; const float* bias;
    const float* g; const float* b2; float* out; int M;
};
__global__ __launch_bounds__(256, 3) void k_ln(LnArgs g0, LnArgs g1) {
    LnArgs P; if (blockIdx.y == 0) P = g0; else P = g1;
    const int Kt = HD;
    __shared__ char sm[BM * 128 + 256 * 128];
    char* sA = sm;
    char* sB = sm + BM * 128;
    const int t = threadIdx.x;
    const int wv = t >> 6, l = t & 63;
    const int l15 = l & 15, lq = l >> 4;
    const int r0 = blockIdx.x * BM;
    const int M = P.M;

    f32x4 acc[16];
    #pragma unroll
    for (int i = 0; i < 16; ++i) acc[i] = (f32x4){0, 0, 0, 0};

    #pragma unroll 1
    for (int c = 0; c < Kt / BK; ++c) {
        const int k0 = c * BK;
        __syncthreads();
        #pragma unroll
        for (int j = 0; j < 2; ++j) {
            int u = t + 256 * j;
            int r = u >> 3, sg = u & 7;
            int gr = r0 + r; if (gr >= M) gr = M - 1;
            uint4 v = *(const uint4*)(P.A + (size_t)gr * Kt + k0 + sg * 8);
            *(uint4*)(sA + r * 128 + ((sg ^ (r & 7)) << 4)) = v;
        }
        #pragma unroll
        for (int j = 0; j < 8; ++j) {
            int u = t + 256 * j;
            int n = u >> 3, sg = u & 7;
            uint4 v = *(const uint4*)(P.WT + (size_t)n * Kt + k0 + sg * 8);
            *(uint4*)(sB + n * 128 + ((sg ^ (n & 7)) << 4)) = v;
        }
        __syncthreads();
        #pragma unroll
        for (int ks = 0; ks < 2; ++ks) {
            int sg = ks * 4 + lq;
            int m = wv * 16 + l15;
            bf16x8 af = *(const bf16x8*)(sA + m * 128 + ((sg ^ (m & 7)) << 4));
            #pragma unroll
            for (int nt = 0; nt < 16; ++nt) {
                int n = nt * 16 + l15;
                bf16x8 bfr = *(const bf16x8*)(sB + n * 128 + ((sg ^ (n & 7)) << 4));
                acc[nt] = __builtin_amdgcn_mfma_f32_16x16x32_bf16(af, bfr, acc[nt], 0, 0, 0);
            }
        }
    }
    #pragma unroll
    for (int nt = 0; nt < 16; ++nt) {
        float bs = P.bias[nt * 16 + l15];
        #pragma unroll
        for (int rg = 0; rg < 4; ++rg) acc[nt][rg] += bs;
    }
    float s0 = 0, s1 = 0, s2 = 0, s3 = 0;
    #pragma unroll
    for (int nt = 0; nt < 16; ++nt) { s0 += acc[nt][0]; s1 += acc[nt][1]; s2 += acc[nt][2]; s3 += acc[nt][3]; }
    #pragma unroll
    for (int off = 1; off < 16; off <<= 1) {
        s0 += __shfl_xor(s0, off, 64); s1 += __shfl_xor(s1, off, 64);
        s2 += __shfl_xor(s2, off, 64); s3 += __shfl_xor(s3, off, 64);
    }
    const float mu0 = s0 * (1.0f / HD), mu1 = s1 * (1.0f / HD),
                mu2 = s2 * (1.0f / HD), mu3 = s3 * (1.0f / HD);
    float q0 = 0, q1 = 0, q2 = 0, q3 = 0;
    #pragma unroll
    for (int nt = 0; nt < 16; ++nt) {
        float d0 = acc[nt][0] - mu0, d1 = acc[nt][1] - mu1,
              d2 = acc[nt][2] - mu2, d3 = acc[nt][3] - mu3;
        q0 += d0 * d0; q1 += d1 * d1; q2 += d2 * d2; q3 += d3 * d3;
    }
    #pragma unroll
    for (int off = 1; off < 16; off <<= 1) {
        q0 += __shfl_xor(q0, off, 64); q1 += __shfl_xor(q1, off, 64);
        q2 += __shfl_xor(q2, off, 64); q3 += __shfl_xor(q3, off, 64);
    }
    const float rs0 = rsqrtf(q0 * (1.0f / HD) + 1e-5f), rs1 = rsqrtf(q1 * (1.0f / HD) + 1e-5f),
                rs2 = rsqrtf(q2 * (1.0f / HD) + 1e-5f), rs3 = rsqrtf(q3 * (1.0f / HD) + 1e-5f);
    const int rowb = r0 + wv * 16 + lq * 4;
    #pragma unroll
    for (int nt = 0; nt < 16; ++nt) {
        int col = nt * 16 + l15;
        float gg = P.g[col], bb = P.b2[col];
        float mu[4] = {mu0, mu1, mu2, mu3};
        float rs[4] = {rs0, rs1, rs2, rs3};
        #pragma unroll
        for (int rg = 0; rg < 4; ++rg) {
            int row = rowb + rg;
            if (row < M)
                P.out[(size_t)row * HD + col] = (acc[nt][rg] - mu[rg]) * rs[rg] * gg + bb;
        }
    }
}

extern "C" void kernel_launch(void* const* d_in, const int* in_sizes, int n_in,
                              void* d_out, int out_size, void* d_ws, size_t ws_size,
                              hipStream_t stream) {
    const float* x_user     = (const float*)d_in[0];
    const float* x_item     = (const float*)d_in[1];
    const int*   ei_ui_src  = (const int*)d_in[2];
    const int*   ei_ui_dst  = (const int*)d_in[3];
    const int*   ei_iu_src  = (const int*)d_in[4];
    const int*   ei_iu_dst  = (const int*)d_in[5];
    const float* lin_user_W = (const float*)d_in[6];
    const float* lin_user_b = (const float*)d_in[7];
    const float* lin_item_W = (const float*)d_in[8];
    const float* lin_item_b = (const float*)d_in[9];
    const float* c0_ui_Wl = (const float*)d_in[10];
    const float* c0_ui_bl = (const float*)d_in[11];
    const float* c0_ui_Wr = (const float*)d_in[12];
    const float* c0_iu_Wl = (const float*)d_in[13];
    const float* c0_iu_bl = (const float*)d_in[14];
    const float* c0_iu_Wr = (const float*)d_in[15];
    const float* c1_ui_Wl = (const float*)d_in[16];
    const float* c1_ui_bl = (const float*)d_in[17];
    const float* c1_ui_Wr = (const float*)d_in[18];
    const float* c1_iu_Wl = (const float*)d_in[19];
    const float* c1_iu_bl = (const float*)d_in[20];
    const float* c1_iu_Wr = (const float*)d_in[21];
    const float* out_user_W = (const float*)d_in[22];
    const float* out_user_b = (const float*)d_in[23];
    const float* out_item_W = (const float*)d_in[24];
    const float* out_item_b = (const float*)d_in[25];
    const float* ln_user_g  = (const float*)d_in[26];
    const float* ln_user_b2 = (const float*)d_in[27];
    const float* ln_item_g  = (const float*)d_in[28];
    const float* ln_item_b2 = (const float*)d_in[29];

    char* ws = (char*)d_ws;
    size_t off = 0;
    auto alloc = [&](size_t bytes) -> void* {
        void* p = ws + off;
        off += (bytes + 255) & ~(size_t)255;
        return p;
    };
    typedef unsigned short u16;
    u16* hu_a = (u16*)alloc((size_t)NUSER * HD * 2);
    u16* hi_a = (u16*)alloc((size_t)NITEM * HD * 2);
    u16* WT_lu   = (u16*)alloc((size_t)HD * DIN * 2);
    u16* WT_li   = (u16*)alloc((size_t)HD * DIN * 2);
    u16* WT_c0ui = (u16*)alloc((size_t)HD * 2 * HD * 2);
    u16* WT_c0iu = (u16*)alloc((size_t)HD * 2 * HD * 2);
    u16* WT_c1ui = (u16*)alloc((size_t)HD * 2 * HD * 2);
    u16* WT_c1iu = (u16*)alloc((size_t)HD * 2 * HD * 2);
    u16* WT_ou   = (u16*)alloc((size_t)HD * HD * 2);
    u16* WT_oi   = (u16*)alloc((size_t)HD * HD * 2);
    int* rp_i  = (int*)alloc((NITEM + 1) * 4);
    int* rp_u  = (int*)alloc((NUSER + 1) * 4);
    int* cur_i = (int*)alloc(NITEM * 4);
    int* cur_u = (int*)alloc(NUSER * 4);
    int* cnt_i = (int*)alloc(NITEM * 4);
    int* cnt_u = (int*)alloc(NUSER * 4);
    int* sl_ui = (int*)alloc((size_t)NEDGE * 4);
    int* sl_iu = (int*)alloc((size_t)NEDGE * 4);
    int* csum_i = (int*)alloc(64 * 4);
    int* csum_u = (int*)alloc(64 * 4);

    // h pong buffers (bf16) live in d_out's 204.8MB; heads overwrite d_out last
    u16* hu_b = (u16*)d_out;
    u16* hi_b = (u16*)d_out + (size_t)NUSER * HD;

    const int MMG = (NUSER + BM - 1) / BM;
    const int NBI = (NITEM + SCHUNK - 1) / SCHUNK;
    const int NBU = (NUSER + SCHUNK - 1) / SCHUNK;

    // ---- CSR build ----
    hipMemsetAsync(cnt_i, 0, NITEM * 4, stream);
    hipMemsetAsync(cnt_u, 0, NUSER * 4, stream);
    k_hist2<<<dim3(1024, 2), 256, 0, stream>>>(ei_ui_dst, cnt_i, ei_iu_dst, cnt_u, NEDGE);
    k_scan_part<<<NBI + NBU, 1024, 0, stream>>>(cnt_i, rp_i, NITEM, NBI, csum_i,
                                                cnt_u, rp_u, NUSER, csum_u);
    k_scan_fin<<<NBI + NBU, 1024, 0, stream>>>(rp_i, cur_i, NITEM, NBI, csum_i,
                                               rp_u, cur_u, NUSER, NBU, csum_u);
    k_scatter2<<<dim3(1024, 2), 256, 0, stream>>>(ei_ui_src, ei_ui_dst, cur_i, sl_ui,
                                                  ei_iu_src, ei_iu_dst, cur_u, sl_iu, NEDGE);

    // ---- weight prep (single launch, 12 jobs) ----
    CvtT12 J;
    const float* srcs[12] = {lin_user_W, lin_item_W,
                             c0_ui_Wl, c0_ui_Wr, c0_iu_Wl, c0_iu_Wr,
                             c1_ui_Wl, c1_ui_Wr, c1_iu_Wl, c1_iu_Wr,
                             out_user_W, out_item_W};
    u16* dsts[12] = {WT_lu, WT_li, WT_c0ui, WT_c0ui, WT_c0iu, WT_c0iu,
                     WT_c1ui, WT_c1ui, WT_c1iu, WT_c1iu, WT_ou, WT_oi};
    int Ks[12]    = {DIN, DIN, HD, HD, HD, HD, HD, HD, HD, HD, HD, HD};
    int Kts[12]   = {DIN, DIN, 2*HD, 2*HD, 2*HD, 2*HD, 2*HD, 2*HD, 2*HD, 2*HD, HD, HD};
    int koffs[12] = {0, 0, 0, HD, 0, HD, 0, HD, 0, HD, 0, 0};
    for (int i = 0; i < 12; ++i) {
        J.src[i] = srcs[i]; J.dst[i] = dsts[i];
        J.K[i] = Ks[i]; J.Kt[i] = Kts[i]; J.koff[i] = koffs[i];
    }
    k_cvtT_all<<<dim3(128, 12), 256, 0, stream>>>(J);

    // ---- input projections (f32 A, one launch) ----
    ProjArgs pu = {x_user, WT_lu, lin_user_b, hu_a, NUSER};
    ProjArgs pi = {x_item, WT_li, lin_item_b, hi_a, NITEM};
    k_proj<<<dim3(MMG, 2), 256, 0, stream>>>(pu, pi);

    // ---- layer 0 (both relations in one launch, gather fused in LDS) ----
    ConvArgs l0ui = {hu_a, hi_a, rp_i, sl_ui, WT_c0ui, c0_ui_bl, hi_b, NITEM};
    ConvArgs l0iu = {hi_a, hu_a, rp_u, sl_iu, WT_c0iu, c0_iu_bl, hu_b, NUSER};
    k_conv<<<dim3(MMG, 2), 256, 0, stream>>>(l0ui, l0iu);

    // ---- layer 1 ----
    ConvArgs l1ui = {hu_b, hi_b, rp_i, sl_ui, WT_c1ui, c1_ui_bl, hi_a, NITEM};
    ConvArgs l1iu = {hi_b, hu_b, rp_u, sl_iu, WT_c1iu, c1_iu_bl, hu_a, NUSER};
    k_conv<<<dim3(MMG, 2), 256, 0, stream>>>(l1ui, l1iu);

    // ---- heads + LayerNorm (one launch, read ws, write d_out) ----
    LnArgs hu = {hu_a, WT_ou, out_user_b, ln_user_g, ln_user_b2, (float*)d_out, NUSER};
    LnArgs hi = {hi_a, WT_oi, out_item_b, ln_item_g, ln_item_b2,
                 (float*)d_out + (size_t)NUSER * HD, NITEM};
    k_ln<<<dim3(MMG, 2), 256, 0, stream>>>(hu, hi);
}

// Round 5
// 1266.214 us; speedup vs baseline: 1.2563x; 1.1246x over previous
//
#include <hip/hip_runtime.h>
#include <math.h>

#define NUSER 100000
#define NITEM 100000
#define NEDGE 800000
#define DIN 128
#define HD 256
#define BM 64
#define BK 64

typedef __attribute__((ext_vector_type(8))) short bf16x8;
typedef __attribute__((ext_vector_type(4))) float f32x4;

__device__ __forceinline__ float gelu_f(float x) {
    return 0.5f * x * (1.0f + erff(x * 0.70710678118654752440f));
}
__device__ __forceinline__ unsigned short f2bf(float f) {
    union { unsigned int i; float f; } v; v.f = f;
    unsigned int r = (v.i + 0x7FFFu + ((v.i >> 16) & 1u)) >> 16;  // RNE
    return (unsigned short)r;
}
__device__ __forceinline__ float bflo(unsigned int p) {
    union { unsigned int i; float f; } v; v.i = p << 16; return v.f;
}
__device__ __forceinline__ float bfhi(unsigned int p) {
    union { unsigned int i; float f; } v; v.i = p & 0xFFFF0000u; return v.f;
}

// ---------------- CSR build ----------------
__global__ void k_hist2(const int* __restrict__ dst0, int* __restrict__ cnt0,
                        const int* __restrict__ dst1, int* __restrict__ cnt1, int n) {
    const int* dst = blockIdx.y ? dst1 : dst0;
    int* cnt = blockIdx.y ? cnt1 : cnt0;
    for (int i = blockIdx.x * blockDim.x + threadIdx.x; i < n; i += gridDim.x * blockDim.x)
        atomicAdd(&cnt[dst[i]], 1);
}

#define SCHUNK 8192
__global__ __launch_bounds__(1024) void k_scan_part(
    const int* __restrict__ cnt0, int* __restrict__ rp0, int n0, int nb0, int* __restrict__ csum0,
    const int* __restrict__ cnt1, int* __restrict__ rp1, int n1, int* __restrict__ csum1) {
    const int b = blockIdx.x;
    const int* cnt; int* rp; int n; int* csum; int chunk;
    if (b < nb0) { cnt = cnt0; rp = rp0; n = n0; csum = csum0; chunk = b; }
    else         { cnt = cnt1; rp = rp1; n = n1; csum = csum1; chunk = b - nb0; }
    const int t = threadIdx.x;
    const int lane = t & 63, wid = t >> 6;
    const int base = chunk * SCHUNK + t * 8;

    int v[8]; int s = 0;
    #pragma unroll
    for (int k = 0; k < 8; ++k) {
        int idx = base + k;
        int x = (idx < n) ? cnt[idx] : 0;
        v[k] = s; s += x;
    }
    int ws = s;
    #pragma unroll
    for (int off = 1; off < 64; off <<= 1) {
        int y = __shfl_up(ws, off, 64);
        if (lane >= off) ws += y;
    }
    __shared__ int wsum[16];
    if (lane == 63) wsum[wid] = ws;
    __syncthreads();
    int wexc = 0;
    for (int w = 0; w < wid; ++w) wexc += wsum[w];
    const int texc = wexc + (ws - s);
    #pragma unroll
    for (int k = 0; k < 8; ++k) {
        int idx = base + k;
        if (idx < n) rp[idx] = texc + v[k];
    }
    if (t == 1023) csum[chunk] = texc + s;
}

__global__ __launch_bounds__(1024) void k_scan_fin(
    int* __restrict__ rp0, int* __restrict__ cur0, int n0, int nb0, const int* __restrict__ csum0,
    int* __restrict__ rp1, int* __restrict__ cur1, int n1, int nb1, const int* __restrict__ csum1) {
    const int b = blockIdx.x;
    int* rp; int* cur; int n; const int* csum; int chunk; int nb;
    if (b < nb0) { rp = rp0; cur = cur0; n = n0; csum = csum0; chunk = b;       nb = nb0; }
    else         { rp = rp1; cur = cur1; n = n1; csum = csum1; chunk = b - nb0; nb = nb1; }
    int off = 0;
    for (int w = 0; w < chunk; ++w) off += csum[w];
    const int t = threadIdx.x;
    const int base = chunk * SCHUNK + t;
    #pragma unroll
    for (int k = 0; k < 8; ++k) {
        int idx = base + k * 1024;
        if (idx < n) { int x = rp[idx] + off; rp[idx] = x; cur[idx] = x; }
    }
    if (chunk == nb - 1 && t == 0) rp[n] = off + csum[nb - 1];
}

__global__ void k_scatter2(const int* __restrict__ s0, const int* __restrict__ d0,
                           int* __restrict__ c0, int* __restrict__ l0,
                           const int* __restrict__ s1, const int* __restrict__ d1,
                           int* __restrict__ c1, int* __restrict__ l1, int n) {
    const int* src = blockIdx.y ? s1 : s0;
    const int* dst = blockIdx.y ? d1 : d0;
    int* cur = blockIdx.y ? c1 : c0;
    int* sl  = blockIdx.y ? l1 : l0;
    for (int i = blockIdx.x * blockDim.x + threadIdx.x; i < n; i += gridDim.x * blockDim.x) {
        int p = atomicAdd(&cur[dst[i]], 1);
        sl[p] = src[i];
    }
}

// ---------------- weight prep: all 12 transposed conversions in ONE launch ----------------
struct CvtT12 {
    const float* src[12];
    unsigned short* dst[12];
    int K[12]; int Kt[12]; int koff[12];
};
__global__ void k_cvtT_all(CvtT12 J) {
    const int job = blockIdx.y;
    const float* src = J.src[job];
    unsigned short* dst = J.dst[job];
    const int K = J.K[job], Kt = J.Kt[job], koff = J.koff[job];
    for (int i = blockIdx.x * blockDim.x + threadIdx.x; i < K * 256; i += gridDim.x * blockDim.x) {
        int k = i >> 8, n = i & 255;
        dst[(size_t)n * Kt + koff + k] = f2bf(src[i]);
    }
}

// ---------------- input projection: f32 A (convert during staging) + GELU, bf16 out ----------------
struct ProjArgs {
    const float* X; const unsigned short* WT; const float* bias;
    unsigned short* out; int M;
};
__global__ __launch_bounds__(256, 3) void k_proj(ProjArgs p0, ProjArgs p1) {
    ProjArgs P; if (blockIdx.y == 0) P = p0; else P = p1;
    const int Kt = DIN;
    __shared__ char sm[BM * 128 + 256 * 128];  // A 8KB + B 32KB
    char* sA = sm;
    char* sB = sm + BM * 128;
    const int t = threadIdx.x;
    const int wv = t >> 6, l = t & 63;
    const int l15 = l & 15, lq = l >> 4;
    const int r0 = blockIdx.x * BM;
    const int M = P.M;

    f32x4 acc[4][4];
    #pragma unroll
    for (int i = 0; i < 4; ++i)
        #pragma unroll
        for (int j = 0; j < 4; ++j) acc[i][j] = (f32x4){0, 0, 0, 0};

    #pragma unroll 1
    for (int c = 0; c < Kt / BK; ++c) {
        const int k0 = c * BK;
        __syncthreads();
        #pragma unroll
        for (int j = 0; j < 2; ++j) {  // A: 512 16B units, from f32 source
            int u = t + 256 * j;
            int r = u >> 3, sg = u & 7;
            int gr = r0 + r; if (gr >= M) gr = M - 1;
            const float* p = P.X + (size_t)gr * Kt + k0 + sg * 8;
            float4 f0 = *(const float4*)(p);
            float4 f1 = *(const float4*)(p + 4);
            uint4 v;
            v.x = (unsigned int)f2bf(f0.x) | ((unsigned int)f2bf(f0.y) << 16);
            v.y = (unsigned int)f2bf(f0.z) | ((unsigned int)f2bf(f0.w) << 16);
            v.z = (unsigned int)f2bf(f1.x) | ((unsigned int)f2bf(f1.y) << 16);
            v.w = (unsigned int)f2bf(f1.z) | ((unsigned int)f2bf(f1.w) << 16);
            *(uint4*)(sA + r * 128 + ((sg ^ (r & 7)) << 4)) = v;
        }
        #pragma unroll
        for (int j = 0; j < 8; ++j) {  // B: 2048 16B units
            int u = t + 256 * j;
            int n = u >> 3, sg = u & 7;
            uint4 v = *(const uint4*)(P.WT + (size_t)n * Kt + k0 + sg * 8);
            *(uint4*)(sB + n * 128 + ((sg ^ (n & 7)) << 4)) = v;
        }
        __syncthreads();
        #pragma unroll
        for (int ks = 0; ks < 2; ++ks) {
            bf16x8 af[4], bfr[4];
            int sg = ks * 4 + lq;
            #pragma unroll
            for (int mt = 0; mt < 4; ++mt) {
                int m = mt * 16 + l15;
                af[mt] = *(const bf16x8*)(sA + m * 128 + ((sg ^ (m & 7)) << 4));
            }
            #pragma unroll
            for (int nt = 0; nt < 4; ++nt) {
                int n = wv * 64 + nt * 16 + l15;
                bfr[nt] = *(const bf16x8*)(sB + n * 128 + ((sg ^ (n & 7)) << 4));
            }
            #pragma unroll
            for (int mt = 0; mt < 4; ++mt)
                #pragma unroll
                for (int nt = 0; nt < 4; ++nt)
                    acc[mt][nt] = __builtin_amdgcn_mfma_f32_16x16x32_bf16(
                        af[mt], bfr[nt], acc[mt][nt], 0, 0, 0);
        }
    }
    #pragma unroll
    for (int nt = 0; nt < 4; ++nt) {
        int col = wv * 64 + nt * 16 + l15;
        float bs = P.bias[col];
        #pragma unroll
        for (int mt = 0; mt < 4; ++mt) {
            int rowb = r0 + mt * 16 + lq * 4;
            #pragma unroll
            for (int rg = 0; rg < 4; ++rg) {
                int row = rowb + rg;
                if (row < M)
                    P.out[(size_t)row * HD + col] = f2bf(gelu_f(acc[mt][nt][rg] + bs));
            }
        }
    }
}

// ---------------- CSR mean gather (standalone, both relations in one launch) ----------------
// one wave per row; lane covers 4 cols (8B); 8 edges in flight for latency
struct GatherArgs {
    const unsigned short* h; const int* rp; const int* sl;
    unsigned short* agg; int nrows;
};
__global__ __launch_bounds__(256, 4) void k_gather2(GatherArgs g0, GatherArgs g1) {
    GatherArgs G; if (blockIdx.y == 0) G = g0; else G = g1;
    const int wv = threadIdx.x >> 6, l = threadIdx.x & 63;
    for (int row = blockIdx.x * 4 + wv; row < G.nrows; row += gridDim.x * 4) {
        int beg = G.rp[row], end = G.rp[row + 1];
        float a0 = 0, a1 = 0, a2 = 0, a3 = 0;
        int e = beg;
        #pragma unroll 1
        for (; e + 8 <= end; e += 8) {
            uint2 v0 = *(const uint2*)(G.h + (size_t)G.sl[e + 0] * HD + 4 * l);
            uint2 v1 = *(const uint2*)(G.h + (size_t)G.sl[e + 1] * HD + 4 * l);
            uint2 v2 = *(const uint2*)(G.h + (size_t)G.sl[e + 2] * HD + 4 * l);
            uint2 v3 = *(const uint2*)(G.h + (size_t)G.sl[e + 3] * HD + 4 * l);
            uint2 v4 = *(const uint2*)(G.h + (size_t)G.sl[e + 4] * HD + 4 * l);
            uint2 v5 = *(const uint2*)(G.h + (size_t)G.sl[e + 5] * HD + 4 * l);
            uint2 v6 = *(const uint2*)(G.h + (size_t)G.sl[e + 6] * HD + 4 * l);
            uint2 v7 = *(const uint2*)(G.h + (size_t)G.sl[e + 7] * HD + 4 * l);
            a0 += bflo(v0.x) + bflo(v1.x) + bflo(v2.x) + bflo(v3.x)
                + bflo(v4.x) + bflo(v5.x) + bflo(v6.x) + bflo(v7.x);
            a1 += bfhi(v0.x) + bfhi(v1.x) + bfhi(v2.x) + bfhi(v3.x)
                + bfhi(v4.x) + bfhi(v5.x) + bfhi(v6.x) + bfhi(v7.x);
            a2 += bflo(v0.y) + bflo(v1.y) + bflo(v2.y) + bflo(v3.y)
                + bflo(v4.y) + bflo(v5.y) + bflo(v6.y) + bflo(v7.y);
            a3 += bfhi(v0.y) + bfhi(v1.y) + bfhi(v2.y) + bfhi(v3.y)
                + bfhi(v4.y) + bfhi(v5.y) + bfhi(v6.y) + bfhi(v7.y);
        }
        #pragma unroll 1
        for (; e + 4 <= end; e += 4) {
            uint2 v0 = *(const uint2*)(G.h + (size_t)G.sl[e + 0] * HD + 4 * l);
            uint2 v1 = *(const uint2*)(G.h + (size_t)G.sl[e + 1] * HD + 4 * l);
            uint2 v2 = *(const uint2*)(G.h + (size_t)G.sl[e + 2] * HD + 4 * l);
            uint2 v3 = *(const uint2*)(G.h + (size_t)G.sl[e + 3] * HD + 4 * l);
            a0 += bflo(v0.x) + bflo(v1.x) + bflo(v2.x) + bflo(v3.x);
            a1 += bfhi(v0.x) + bfhi(v1.x) + bfhi(v2.x) + bfhi(v3.x);
            a2 += bflo(v0.y) + bflo(v1.y) + bflo(v2.y) + bflo(v3.y);
            a3 += bfhi(v0.y) + bfhi(v1.y) + bfhi(v2.y) + bfhi(v3.y);
        }
        #pragma unroll 1
        for (; e < end; ++e) {
            uint2 v = *(const uint2*)(G.h + (size_t)G.sl[e] * HD + 4 * l);
            a0 += bflo(v.x); a1 += bfhi(v.x); a2 += bflo(v.y); a3 += bfhi(v.y);
        }
        float inv = 1.0f / fmaxf((float)(end - beg), 1.0f);
        unsigned int lo = (unsigned int)f2bf(a0 * inv) | ((unsigned int)f2bf(a1 * inv) << 16);
        unsigned int hi = (unsigned int)f2bf(a2 * inv) | ((unsigned int)f2bf(a3 * inv) << 16);
        uint2 o = {lo, hi};
        *(uint2*)(G.agg + (size_t)row * HD + 4 * l) = o;
    }
}

// ---------------- conv GEMM (both relations in one launch): GELU([agg|h_dst] @ W + b) ----------------
// LDS-staged A (8KB) + B (32KB), xor-swizzled; chunks 0-3 stage from A1=agg, 4-7 from A2=h_dst.
struct MmArgs {
    const unsigned short* A1; const unsigned short* A2;
    const unsigned short* WT; const float* bias;
    unsigned short* out; int M;
};
__global__ __launch_bounds__(256, 3) void k_mm2(MmArgs m0, MmArgs m1) {
    MmArgs P; if (blockIdx.y == 0) P = m0; else P = m1;
    __shared__ char sm[BM * 128 + 256 * 128];  // A 8KB + B 32KB
    char* sA = sm;
    char* sB = sm + BM * 128;
    const int t = threadIdx.x;
    const int wv = t >> 6, l = t & 63;
    const int l15 = l & 15, lq = l >> 4;
    const int r0 = blockIdx.x * BM;
    const int M = P.M;

    f32x4 acc[4][4];
    #pragma unroll
    for (int i = 0; i < 4; ++i)
        #pragma unroll
        for (int j = 0; j < 4; ++j) acc[i][j] = (f32x4){0, 0, 0, 0};

    #pragma unroll 1
    for (int c = 0; c < 8; ++c) {
        const unsigned short* Ap = (c < 4) ? P.A1 : P.A2;
        const int kloc = (c < 4) ? c * BK : (c - 4) * BK;
        __syncthreads();  // WAR: prev iter's frag reads before restage
        #pragma unroll
        for (int j = 0; j < 2; ++j) {  // A: 512 16B units
            int u = t + 256 * j;
            int r = u >> 3, sg = u & 7;
            int gr = r0 + r; if (gr >= M) gr = M - 1;
            uint4 v = *(const uint4*)(Ap + (size_t)gr * HD + kloc + sg * 8);
            *(uint4*)(sA + r * 128 + ((sg ^ (r & 7)) << 4)) = v;
        }
        #pragma unroll
        for (int j = 0; j < 8; ++j) {  // B: 2048 16B units, WT is [256][512]
            int u = t + 256 * j;
            int n = u >> 3, sg = u & 7;
            uint4 v = *(const uint4*)(P.WT + (size_t)n * 512 + c * BK + sg * 8);
            *(uint4*)(sB + n * 128 + ((sg ^ (n & 7)) << 4)) = v;
        }
        __syncthreads();
        #pragma unroll
        for (int ks = 0; ks < 2; ++ks) {
            bf16x8 af[4], bfr[4];
            int sg = ks * 4 + lq;
            #pragma unroll
            for (int mt = 0; mt < 4; ++mt) {
                int m = mt * 16 + l15;
                af[mt] = *(const bf16x8*)(sA + m * 128 + ((sg ^ (m & 7)) << 4));
            }
            #pragma unroll
            for (int nt = 0; nt < 4; ++nt) {
                int n = wv * 64 + nt * 16 + l15;
                bfr[nt] = *(const bf16x8*)(sB + n * 128 + ((sg ^ (n & 7)) << 4));
            }
            #pragma unroll
            for (int mt = 0; mt < 4; ++mt)
                #pragma unroll
                for (int nt = 0; nt < 4; ++nt)
                    acc[mt][nt] = __builtin_amdgcn_mfma_f32_16x16x32_bf16(
                        af[mt], bfr[nt], acc[mt][nt], 0, 0, 0);
        }
    }
    #pragma unroll
    for (int nt = 0; nt < 4; ++nt) {
        int col = wv * 64 + nt * 16 + l15;
        float bs = P.bias[col];
        #pragma unroll
        for (int mt = 0; mt < 4; ++mt) {
            int rowb = r0 + mt * 16 + lq * 4;
            #pragma unroll
            for (int rg = 0; rg < 4; ++rg) {
                int row = rowb + rg;
                if (row < M)
                    P.out[(size_t)row * HD + col] = f2bf(gelu_f(acc[mt][nt][rg] + bs));
            }
        }
    }
}

// ---------------- head GEMM + LayerNorm epilogue, f32 out ----------------
struct LnArgs {
    const unsigned short* A; const unsigned short* WT; const float* bias;
    const float* g; const float* b2; float* out; int M;
};
__global__ __launch_bounds__(256, 3) void k_ln(LnArgs g0, LnArgs g1) {
    LnArgs P; if (blockIdx.y == 0) P = g0; else P = g1;
    const int Kt = HD;
    __shared__ char sm[BM * 128 + 256 * 128];
    char* sA = sm;
    char* sB = sm + BM * 128;
    const int t = threadIdx.x;
    const int wv = t >> 6, l = t & 63;
    const int l15 = l & 15, lq = l >> 4;
    const int r0 = blockIdx.x * BM;
    const int M = P.M;

    f32x4 acc[16];
    #pragma unroll
    for (int i = 0; i < 16; ++i) acc[i] = (f32x4){0, 0, 0, 0};

    #pragma unroll 1
    for (int c = 0; c < Kt / BK; ++c) {
        const int k0 = c * BK;
        __syncthreads();
        #pragma unroll
        for (int j = 0; j < 2; ++j) {
            int u = t + 256 * j;
            int r = u >> 3, sg = u & 7;
            int gr = r0 + r; if (gr >= M) gr = M - 1;
            uint4 v = *(const uint4*)(P.A + (size_t)gr * Kt + k0 + sg * 8);
            *(uint4*)(sA + r * 128 + ((sg ^ (r & 7)) << 4)) = v;
        }
        #pragma unroll
        for (int j = 0; j < 8; ++j) {
            int u = t + 256 * j;
            int n = u >> 3, sg = u & 7;
            uint4 v = *(const uint4*)(P.WT + (size_t)n * Kt + k0 + sg * 8);
            *(uint4*)(sB + n * 128 + ((sg ^ (n & 7)) << 4)) = v;
        }
        __syncthreads();
        #pragma unroll
        for (int ks = 0; ks < 2; ++ks) {
            int sg = ks * 4 + lq;
            int m = wv * 16 + l15;
            bf16x8 af = *(const bf16x8*)(sA + m * 128 + ((sg ^ (m & 7)) << 4));
            #pragma unroll
            for (int nt = 0; nt < 16; ++nt) {
                int n = nt * 16 + l15;
                bf16x8 bfr = *(const bf16x8*)(sB + n * 128 + ((sg ^ (n & 7)) << 4));
                acc[nt] = __builtin_amdgcn_mfma_f32_16x16x32_bf16(af, bfr, acc[nt], 0, 0, 0);
            }
        }
    }
    #pragma unroll
    for (int nt = 0; nt < 16; ++nt) {
        float bs = P.bias[nt * 16 + l15];
        #pragma unroll
        for (int rg = 0; rg < 4; ++rg) acc[nt][rg] += bs;
    }
    float s0 = 0, s1 = 0, s2 = 0, s3 = 0;
    #pragma unroll
    for (int nt = 0; nt < 16; ++nt) { s0 += acc[nt][0]; s1 += acc[nt][1]; s2 += acc[nt][2]; s3 += acc[nt][3]; }
    #pragma unroll
    for (int off = 1; off < 16; off <<= 1) {
        s0 += __shfl_xor(s0, off, 64); s1 += __shfl_xor(s1, off, 64);
        s2 += __shfl_xor(s2, off, 64); s3 += __shfl_xor(s3, off, 64);
    }
    const float mu0 = s0 * (1.0f / HD), mu1 = s1 * (1.0f / HD),
                mu2 = s2 * (1.0f / HD), mu3 = s3 * (1.0f / HD);
    float q0 = 0, q1 = 0, q2 = 0, q3 = 0;
    #pragma unroll
    for (int nt = 0; nt < 16; ++nt) {
        float d0 = acc[nt][0] - mu0, d1 = acc[nt][1] - mu1,
              d2 = acc[nt][2] - mu2, d3 = acc[nt][3] - mu3;
        q0 += d0 * d0; q1 += d1 * d1; q2 += d2 * d2; q3 += d3 * d3;
    }
    #pragma unroll
    for (int off = 1; off < 16; off <<= 1) {
        q0 += __shfl_xor(q0, off, 64); q1 += __shfl_xor(q1, off, 64);
        q2 += __shfl_xor(q2, off, 64); q3 += __shfl_xor(q3, off, 64);
    }
    const float rs0 = rsqrtf(q0 * (1.0f / HD) + 1e-5f), rs1 = rsqrtf(q1 * (1.0f / HD) + 1e-5f),
                rs2 = rsqrtf(q2 * (1.0f / HD) + 1e-5f), rs3 = rsqrtf(q3 * (1.0f / HD) + 1e-5f);
    const int rowb = r0 + wv * 16 + lq * 4;
    #pragma unroll
    for (int nt = 0; nt < 16; ++nt) {
        int col = nt * 16 + l15;
        float gg = P.g[col], bb = P.b2[col];
        float mu[4] = {mu0, mu1, mu2, mu3};
        float rs[4] = {rs0, rs1, rs2, rs3};
        #pragma unroll
        for (int rg = 0; rg < 4; ++rg) {
            int row = rowb + rg;
            if (row < M)
                P.out[(size_t)row * HD + col] = (acc[nt][rg] - mu[rg]) * rs[rg] * gg + bb;
        }
    }
}

extern "C" void kernel_launch(void* const* d_in, const int* in_sizes, int n_in,
                              void* d_out, int out_size, void* d_ws, size_t ws_size,
                              hipStream_t stream) {
    const float* x_user     = (const float*)d_in[0];
    const float* x_item     = (const float*)d_in[1];
    const int*   ei_ui_src  = (const int*)d_in[2];
    const int*   ei_ui_dst  = (const int*)d_in[3];
    const int*   ei_iu_src  = (const int*)d_in[4];
    const int*   ei_iu_dst  = (const int*)d_in[5];
    const float* lin_user_W = (const float*)d_in[6];
    const float* lin_user_b = (const float*)d_in[7];
    const float* lin_item_W = (const float*)d_in[8];
    const float* lin_item_b = (const float*)d_in[9];
    const float* c0_ui_Wl = (const float*)d_in[10];
    const float* c0_ui_bl = (const float*)d_in[11];
    const float* c0_ui_Wr = (const float*)d_in[12];
    const float* c0_iu_Wl = (const float*)d_in[13];
    const float* c0_iu_bl = (const float*)d_in[14];
    const float* c0_iu_Wr = (const float*)d_in[15];
    const float* c1_ui_Wl = (const float*)d_in[16];
    const float* c1_ui_bl = (const float*)d_in[17];
    const float* c1_ui_Wr = (const float*)d_in[18];
    const float* c1_iu_Wl = (const float*)d_in[19];
    const float* c1_iu_bl = (const float*)d_in[20];
    const float* c1_iu_Wr = (const float*)d_in[21];
    const float* out_user_W = (const float*)d_in[22];
    const float* out_user_b = (const float*)d_in[23];
    const float* out_item_W = (const float*)d_in[24];
    const float* out_item_b = (const float*)d_in[25];
    const float* ln_user_g  = (const float*)d_in[26];
    const float* ln_user_b2 = (const float*)d_in[27];
    const float* ln_item_g  = (const float*)d_in[28];
    const float* ln_item_b2 = (const float*)d_in[29];

    char* ws = (char*)d_ws;
    size_t off = 0;
    auto alloc = [&](size_t bytes) -> void* {
        void* p = ws + off;
        off += (bytes + 255) & ~(size_t)255;
        return p;
    };
    typedef unsigned short u16;
    u16* hu_a = (u16*)alloc((size_t)NUSER * HD * 2);
    u16* hi_a = (u16*)alloc((size_t)NITEM * HD * 2);
    u16* aggI = (u16*)alloc((size_t)NITEM * HD * 2);   // mean msgs into items (ui)
    u16* aggU = (u16*)alloc((size_t)NUSER * HD * 2);   // mean msgs into users (iu)
    u16* WT_lu   = (u16*)alloc((size_t)HD * DIN * 2);
    u16* WT_li   = (u16*)alloc((size_t)HD * DIN * 2);
    u16* WT_c0ui = (u16*)alloc((size_t)HD * 2 * HD * 2);
    u16* WT_c0iu = (u16*)alloc((size_t)HD * 2 * HD * 2);
    u16* WT_c1ui = (u16*)alloc((size_t)HD * 2 * HD * 2);
    u16* WT_c1iu = (u16*)alloc((size_t)HD * 2 * HD * 2);
    u16* WT_ou   = (u16*)alloc((size_t)HD * HD * 2);
    u16* WT_oi   = (u16*)alloc((size_t)HD * HD * 2);
    int* rp_i  = (int*)alloc((NITEM + 1) * 4);
    int* rp_u  = (int*)alloc((NUSER + 1) * 4);
    int* cur_i = (int*)alloc(NITEM * 4);
    int* cur_u = (int*)alloc(NUSER * 4);
    int* cnt_i = (int*)alloc(NITEM * 4);
    int* cnt_u = (int*)alloc(NUSER * 4);
    int* sl_ui = (int*)alloc((size_t)NEDGE * 4);
    int* sl_iu = (int*)alloc((size_t)NEDGE * 4);
    int* csum_i = (int*)alloc(64 * 4);
    int* csum_u = (int*)alloc(64 * 4);

    // h pong buffers (bf16) live in d_out's 204.8MB; heads overwrite d_out last
    u16* hu_b = (u16*)d_out;
    u16* hi_b = (u16*)d_out + (size_t)NUSER * HD;

    const int MMG = (NUSER + BM - 1) / BM;
    const int NBI = (NITEM + SCHUNK - 1) / SCHUNK;
    const int NBU = (NUSER + SCHUNK - 1) / SCHUNK;

    // ---- CSR build ----
    hipMemsetAsync(cnt_i, 0, NITEM * 4, stream);
    hipMemsetAsync(cnt_u, 0, NUSER * 4, stream);
    k_hist2<<<dim3(1024, 2), 256, 0, stream>>>(ei_ui_dst, cnt_i, ei_iu_dst, cnt_u, NEDGE);
    k_scan_part<<<NBI + NBU, 1024, 0, stream>>>(cnt_i, rp_i, NITEM, NBI, csum_i,
                                                cnt_u, rp_u, NUSER, csum_u);
    k_scan_fin<<<NBI + NBU, 1024, 0, stream>>>(rp_i, cur_i, NITEM, NBI, csum_i,
                                               rp_u, cur_u, NUSER, NBU, csum_u);
    k_scatter2<<<dim3(1024, 2), 256, 0, stream>>>(ei_ui_src, ei_ui_dst, cur_i, sl_ui,
                                                  ei_iu_src, ei_iu_dst, cur_u, sl_iu, NEDGE);

    // ---- weight prep (single launch, 12 jobs) ----
    CvtT12 J;
    const float* srcs[12] = {lin_user_W, lin_item_W,
                             c0_ui_Wl, c0_ui_Wr, c0_iu_Wl, c0_iu_Wr,
                             c1_ui_Wl, c1_ui_Wr, c1_iu_Wl, c1_iu_Wr,
                             out_user_W, out_item_W};
    u16* dsts[12] = {WT_lu, WT_li, WT_c0ui, WT_c0ui, WT_c0iu, WT_c0iu,
                     WT_c1ui, WT_c1ui, WT_c1iu, WT_c1iu, WT_ou, WT_oi};
    int Ks[12]    = {DIN, DIN, HD, HD, HD, HD, HD, HD, HD, HD, HD, HD};
    int Kts[12]   = {DIN, DIN, 2*HD, 2*HD, 2*HD, 2*HD, 2*HD, 2*HD, 2*HD, 2*HD, HD, HD};
    int koffs[12] = {0, 0, 0, HD, 0, HD, 0, HD, 0, HD, 0, 0};
    for (int i = 0; i < 12; ++i) {
        J.src[i] = srcs[i]; J.dst[i] = dsts[i];
        J.K[i] = Ks[i]; J.Kt[i] = Kts[i]; J.koff[i] = koffs[i];
    }
    k_cvtT_all<<<dim3(128, 12), 256, 0, stream>>>(J);

    // ---- input projections (f32 A, one launch) ----
    ProjArgs pu = {x_user, WT_lu, lin_user_b, hu_a, NUSER};
    ProjArgs pi = {x_item, WT_li, lin_item_b, hi_a, NITEM};
    k_proj<<<dim3(MMG, 2), 256, 0, stream>>>(pu, pi);

    // ---- layer 0: both gathers in one launch, both conv GEMMs in one launch ----
    GatherArgs g0i = {hu_a, rp_i, sl_ui, aggI, NITEM};
    GatherArgs g0u = {hi_a, rp_u, sl_iu, aggU, NUSER};
    k_gather2<<<dim3(4096, 2), 256, 0, stream>>>(g0i, g0u);
    MmArgs m0i = {aggI, hi_a, WT_c0ui, c0_ui_bl, hi_b, NITEM};
    MmArgs m0u = {aggU, hu_a, WT_c0iu, c0_iu_bl, hu_b, NUSER};
    k_mm2<<<dim3(MMG, 2), 256, 0, stream>>>(m0i, m0u);

    // ---- layer 1 ----
    GatherArgs g1i = {hu_b, rp_i, sl_ui, aggI, NITEM};
    GatherArgs g1u = {hi_b, rp_u, sl_iu, aggU, NUSER};
    k_gather2<<<dim3(4096, 2), 256, 0, stream>>>(g1i, g1u);
    MmArgs m1i = {aggI, hi_b, WT_c1ui, c1_ui_bl, hi_a, NITEM};
    MmArgs m1u = {aggU, hu_b, WT_c1iu, c1_iu_bl, hu_a, NUSER};
    k_mm2<<<dim3(MMG, 2), 256, 0, stream>>>(m1i, m1u);

    // ---- heads + LayerNorm (one launch, read ws, write d_out) ----
    LnArgs hu = {hu_a, WT_ou, out_user_b, ln_user_g, ln_user_b2, (float*)d_out, NUSER};
    LnArgs hi = {hi_a, WT_oi, out_item_b, ln_item_g, ln_item_b2,
                 (float*)d_out + (size_t)NUSER * HD, NITEM};
    k_ln<<<dim3(MMG, 2), 256, 0, stream>>>(hu, hi);
}

// Round 7
// 1210.880 us; speedup vs baseline: 1.3137x; 1.0457x over previous
//
#include <hip/hip_runtime.h>
#include <math.h>

#define NUSER 100000
#define NITEM 100000
#define NEDGE 800000
#define DIN 128
#define HD 256
#define BM 64
#define BK 64

typedef __attribute__((ext_vector_type(8))) short bf16x8;
typedef __attribute__((ext_vector_type(4))) float f32x4;

__device__ __forceinline__ float gelu_f(float x) {
    return 0.5f * x * (1.0f + erff(x * 0.70710678118654752440f));
}
__device__ __forceinline__ unsigned short f2bf(float f) {
    union { unsigned int i; float f; } v; v.f = f;
    unsigned int r = (v.i + 0x7FFFu + ((v.i >> 16) & 1u)) >> 16;  // RNE
    return (unsigned short)r;
}
__device__ __forceinline__ float bflo(unsigned int p) {
    union { unsigned int i; float f; } v; v.i = p << 16; return v.f;
}
__device__ __forceinline__ float bfhi(unsigned int p) {
    union { unsigned int i; float f; } v; v.i = p & 0xFFFF0000u; return v.f;
}
// async global->LDS, 16B per lane; dest = lds base (wave-uniform) + lane*16
__device__ __forceinline__ void gl_lds16(const void* g, void* l) {
    __builtin_amdgcn_global_load_lds(
        (const __attribute__((address_space(1))) unsigned int*)g,
        (__attribute__((address_space(3))) unsigned int*)l, 16, 0, 0);
}

// ---------------- CSR build ----------------
__global__ void k_hist2(const int* __restrict__ dst0, int* __restrict__ cnt0,
                        const int* __restrict__ dst1, int* __restrict__ cnt1, int n) {
    const int* dst = blockIdx.y ? dst1 : dst0;
    int* cnt = blockIdx.y ? cnt1 : cnt0;
    for (int i = blockIdx.x * blockDim.x + threadIdx.x; i < n; i += gridDim.x * blockDim.x)
        atomicAdd(&cnt[dst[i]], 1);
}

#define SCHUNK 8192
__global__ __launch_bounds__(1024) void k_scan_part(
    const int* __restrict__ cnt0, int* __restrict__ rp0, int n0, int nb0, int* __restrict__ csum0,
    const int* __restrict__ cnt1, int* __restrict__ rp1, int n1, int* __restrict__ csum1) {
    const int b = blockIdx.x;
    const int* cnt; int* rp; int n; int* csum; int chunk;
    if (b < nb0) { cnt = cnt0; rp = rp0; n = n0; csum = csum0; chunk = b; }
    else         { cnt = cnt1; rp = rp1; n = n1; csum = csum1; chunk = b - nb0; }
    const int t = threadIdx.x;
    const int lane = t & 63, wid = t >> 6;
    const int base = chunk * SCHUNK + t * 8;

    int v[8]; int s = 0;
    #pragma unroll
    for (int k = 0; k < 8; ++k) {
        int idx = base + k;
        int x = (idx < n) ? cnt[idx] : 0;
        v[k] = s; s += x;
    }
    int ws = s;
    #pragma unroll
    for (int off = 1; off < 64; off <<= 1) {
        int y = __shfl_up(ws, off, 64);
        if (lane >= off) ws += y;
    }
    __shared__ int wsum[16];
    if (lane == 63) wsum[wid] = ws;
    __syncthreads();
    int wexc = 0;
    for (int w = 0; w < wid; ++w) wexc += wsum[w];
    const int texc = wexc + (ws - s);
    #pragma unroll
    for (int k = 0; k < 8; ++k) {
        int idx = base + k;
        if (idx < n) rp[idx] = texc + v[k];
    }
    if (t == 1023) csum[chunk] = texc + s;
}

__global__ __launch_bounds__(1024) void k_scan_fin(
    int* __restrict__ rp0, int* __restrict__ cur0, int n0, int nb0, const int* __restrict__ csum0,
    int* __restrict__ rp1, int* __restrict__ cur1, int n1, int nb1, const int* __restrict__ csum1) {
    const int b = blockIdx.x;
    int* rp; int* cur; int n; const int* csum; int chunk; int nb;
    if (b < nb0) { rp = rp0; cur = cur0; n = n0; csum = csum0; chunk = b;       nb = nb0; }
    else         { rp = rp1; cur = cur1; n = n1; csum = csum1; chunk = b - nb0; nb = nb1; }
    int off = 0;
    for (int w = 0; w < chunk; ++w) off += csum[w];
    const int t = threadIdx.x;
    const int base = chunk * SCHUNK + t;
    #pragma unroll
    for (int k = 0; k < 8; ++k) {
        int idx = base + k * 1024;
        if (idx < n) { int x = rp[idx] + off; rp[idx] = x; cur[idx] = x; }
    }
    if (chunk == nb - 1 && t == 0) rp[n] = off + csum[nb - 1];
}

__global__ void k_scatter2(const int* __restrict__ s0, const int* __restrict__ d0,
                           int* __restrict__ c0, int* __restrict__ l0,
                           const int* __restrict__ s1, const int* __restrict__ d1,
                           int* __restrict__ c1, int* __restrict__ l1, int n) {
    const int* src = blockIdx.y ? s1 : s0;
    const int* dst = blockIdx.y ? d1 : d0;
    int* cur = blockIdx.y ? c1 : c0;
    int* sl  = blockIdx.y ? l1 : l0;
    for (int i = blockIdx.x * blockDim.x + threadIdx.x; i < n; i += gridDim.x * blockDim.x) {
        int p = atomicAdd(&cur[dst[i]], 1);
        sl[p] = src[i];
    }
}

// ---------------- weight prep: all 12 transposed conversions in ONE launch ----------------
struct CvtT12 {
    const float* src[12];
    unsigned short* dst[12];
    int K[12]; int Kt[12]; int koff[12];
};
__global__ void k_cvtT_all(CvtT12 J) {
    const int job = blockIdx.y;
    const float* src = J.src[job];
    unsigned short* dst = J.dst[job];
    const int K = J.K[job], Kt = J.Kt[job], koff = J.koff[job];
    for (int i = blockIdx.x * blockDim.x + threadIdx.x; i < K * 256; i += gridDim.x * blockDim.x) {
        int k = i >> 8, n = i & 255;
        dst[(size_t)n * Kt + koff + k] = f2bf(src[i]);
    }
}

// ---------------- input projection: f32 A (convert during staging) + GELU, bf16 out ----------------
struct ProjArgs {
    const float* X; const unsigned short* WT; const float* bias;
    unsigned short* out; int M;
};
__global__ __launch_bounds__(256, 3) void k_proj(ProjArgs p0, ProjArgs p1) {
    ProjArgs P; if (blockIdx.y == 0) P = p0; else P = p1;
    const int Kt = DIN;
    __shared__ char sm[BM * 128 + 256 * 128];  // A 8KB + B 32KB
    char* sA = sm;
    char* sB = sm + BM * 128;
    const int t = threadIdx.x;
    const int wv = t >> 6, l = t & 63;
    const int l15 = l & 15, lq = l >> 4;
    const int r0 = blockIdx.x * BM;
    const int M = P.M;

    f32x4 acc[4][4];
    #pragma unroll
    for (int i = 0; i < 4; ++i)
        #pragma unroll
        for (int j = 0; j < 4; ++j) acc[i][j] = (f32x4){0, 0, 0, 0};

    #pragma unroll 1
    for (int c = 0; c < Kt / BK; ++c) {
        const int k0 = c * BK;
        __syncthreads();
        #pragma unroll
        for (int j = 0; j < 2; ++j) {  // A: 512 16B units, from f32 source (convert)
            int u = t + 256 * j;
            int r = u >> 3, sg = u & 7;
            int gr = r0 + r; if (gr >= M) gr = M - 1;
            const float* p = P.X + (size_t)gr * Kt + k0 + sg * 8;
            float4 f0 = *(const float4*)(p);
            float4 f1 = *(const float4*)(p + 4);
            uint4 v;
            v.x = (unsigned int)f2bf(f0.x) | ((unsigned int)f2bf(f0.y) << 16);
            v.y = (unsigned int)f2bf(f0.z) | ((unsigned int)f2bf(f0.w) << 16);
            v.z = (unsigned int)f2bf(f1.x) | ((unsigned int)f2bf(f1.y) << 16);
            v.w = (unsigned int)f2bf(f1.z) | ((unsigned int)f2bf(f1.w) << 16);
            *(uint4*)(sA + r * 128 + ((sg ^ (r & 7)) << 4)) = v;
        }
        #pragma unroll
        for (int j = 0; j < 8; ++j) {  // B: async, linear dest + inv-swizzled src
            int u = (wv * 8 + j) * 64 + l;
            int n = u >> 3, sg = (u & 7) ^ (n & 7);
            gl_lds16(P.WT + (size_t)n * Kt + k0 + sg * 8, sB + (wv * 8 + j) * 1024);
        }
        __syncthreads();
        #pragma unroll
        for (int ks = 0; ks < 2; ++ks) {
            bf16x8 af[4], bfr[4];
            int sg = ks * 4 + lq;
            #pragma unroll
            for (int mt = 0; mt < 4; ++mt) {
                int m = mt * 16 + l15;
                af[mt] = *(const bf16x8*)(sA + m * 128 + ((sg ^ (m & 7)) << 4));
            }
            #pragma unroll
            for (int nt = 0; nt < 4; ++nt) {
                int n = wv * 64 + nt * 16 + l15;
                bfr[nt] = *(const bf16x8*)(sB + n * 128 + ((sg ^ (n & 7)) << 4));
            }
            #pragma unroll
            for (int mt = 0; mt < 4; ++mt)
                #pragma unroll
                for (int nt = 0; nt < 4; ++nt)
                    acc[mt][nt] = __builtin_amdgcn_mfma_f32_16x16x32_bf16(
                        af[mt], bfr[nt], acc[mt][nt], 0, 0, 0);
        }
    }
    #pragma unroll
    for (int nt = 0; nt < 4; ++nt) {
        int col = wv * 64 + nt * 16 + l15;
        float bs = P.bias[col];
        #pragma unroll
        for (int mt = 0; mt < 4; ++mt) {
            int rowb = r0 + mt * 16 + lq * 4;
            #pragma unroll
            for (int rg = 0; rg < 4; ++rg) {
                int row = rowb + rg;
                if (row < M)
                    P.out[(size_t)row * HD + col] = f2bf(gelu_f(acc[mt][nt][rg] + bs));
            }
        }
    }
}

// ---------------- CSR mean gather (standalone, both relations in one launch) ----------------
struct GatherArgs {
    const unsigned short* h; const int* rp; const int* sl;
    unsigned short* agg; int nrows;
};
__global__ __launch_bounds__(256, 4) void k_gather2(GatherArgs g0, GatherArgs g1) {
    GatherArgs G; if (blockIdx.y == 0) G = g0; else G = g1;
    const int wv = threadIdx.x >> 6, l = threadIdx.x & 63;
    for (int row = blockIdx.x * 4 + wv; row < G.nrows; row += gridDim.x * 4) {
        int beg = G.rp[row], end = G.rp[row + 1];
        float a0 = 0, a1 = 0, a2 = 0, a3 = 0;
        int e = beg;
        #pragma unroll 1
        for (; e + 8 <= end; e += 8) {
            uint2 v0 = *(const uint2*)(G.h + (size_t)G.sl[e + 0] * HD + 4 * l);
            uint2 v1 = *(const uint2*)(G.h + (size_t)G.sl[e + 1] * HD + 4 * l);
            uint2 v2 = *(const uint2*)(G.h + (size_t)G.sl[e + 2] * HD + 4 * l);
            uint2 v3 = *(const uint2*)(G.h + (size_t)G.sl[e + 3] * HD + 4 * l);
            uint2 v4 = *(const uint2*)(G.h + (size_t)G.sl[e + 4] * HD + 4 * l);
            uint2 v5 = *(const uint2*)(G.h + (size_t)G.sl[e + 5] * HD + 4 * l);
            uint2 v6 = *(const uint2*)(G.h + (size_t)G.sl[e + 6] * HD + 4 * l);
            uint2 v7 = *(const uint2*)(G.h + (size_t)G.sl[e + 7] * HD + 4 * l);
            a0 += bflo(v0.x) + bflo(v1.x) + bflo(v2.x) + bflo(v3.x)
                + bflo(v4.x) + bflo(v5.x) + bflo(v6.x) + bflo(v7.x);
            a1 += bfhi(v0.x) + bfhi(v1.x) + bfhi(v2.x) + bfhi(v3.x)
                + bfhi(v4.x) + bfhi(v5.x) + bfhi(v6.x) + bfhi(v7.x);
            a2 += bflo(v0.y) + bflo(v1.y) + bflo(v2.y) + bflo(v3.y)
                + bflo(v4.y) + bflo(v5.y) + bflo(v6.y) + bflo(v7.y);
            a3 += bfhi(v0.y) + bfhi(v1.y) + bfhi(v2.y) + bfhi(v3.y)
                + bfhi(v4.y) + bfhi(v5.y) + bfhi(v6.y) + bfhi(v7.y);
        }
        #pragma unroll 1
        for (; e + 4 <= end; e += 4) {
            uint2 v0 = *(const uint2*)(G.h + (size_t)G.sl[e + 0] * HD + 4 * l);
            uint2 v1 = *(const uint2*)(G.h + (size_t)G.sl[e + 1] * HD + 4 * l);
            uint2 v2 = *(const uint2*)(G.h + (size_t)G.sl[e + 2] * HD + 4 * l);
            uint2 v3 = *(const uint2*)(G.h + (size_t)G.sl[e + 3] * HD + 4 * l);
            a0 += bflo(v0.x) + bflo(v1.x) + bflo(v2.x) + bflo(v3.x);
            a1 += bfhi(v0.x) + bfhi(v1.x) + bfhi(v2.x) + bfhi(v3.x);
            a2 += bflo(v0.y) + bflo(v1.y) + bflo(v2.y) + bflo(v3.y);
            a3 += bfhi(v0.y) + bfhi(v1.y) + bfhi(v2.y) + bfhi(v3.y);
        }
        #pragma unroll 1
        for (; e < end; ++e) {
            uint2 v = *(const uint2*)(G.h + (size_t)G.sl[e] * HD + 4 * l);
            a0 += bflo(v.x); a1 += bfhi(v.x); a2 += bflo(v.y); a3 += bfhi(v.y);
        }
        float inv = 1.0f / fmaxf((float)(end - beg), 1.0f);
        unsigned int lo = (unsigned int)f2bf(a0 * inv) | ((unsigned int)f2bf(a1 * inv) << 16);
        unsigned int hi = (unsigned int)f2bf(a2 * inv) | ((unsigned int)f2bf(a3 * inv) << 16);
        uint2 o = {lo, hi};
        *(uint2*)(G.agg + (size_t)row * HD + 4 * l) = o;
    }
}

// ---------------- conv GEMM (both relations): GELU([agg|h_dst] @ W + b) ----------------
// global_load_lds staging (linear LDS dest, inverse-swizzled global src); readers use
// the same xor-swizzle as before. 40KB LDS x 4 blocks = 160KB/CU.
struct MmArgs {
    const unsigned short* A1; const unsigned short* A2;
    const unsigned short* WT; const float* bias;
    unsigned short* out; int M;
};
__global__ __launch_bounds__(256, 4) void k_mm2(MmArgs m0, MmArgs m1) {
    MmArgs P; if (blockIdx.y == 0) P = m0; else P = m1;
    __shared__ char sm[BM * 128 + 256 * 128];  // A 8KB + B 32KB
    char* sA = sm;
    char* sB = sm + BM * 128;
    const int t = threadIdx.x;
    const int wv = t >> 6, l = t & 63;
    const int l15 = l & 15, lq = l >> 4;
    const int r0 = blockIdx.x * BM;
    const int M = P.M;

    f32x4 acc[4][4];
    #pragma unroll
    for (int i = 0; i < 4; ++i)
        #pragma unroll
        for (int j = 0; j < 4; ++j) acc[i][j] = (f32x4){0, 0, 0, 0};

    #pragma unroll 1
    for (int c = 0; c < 8; ++c) {
        const unsigned short* Ap = (c < 4) ? P.A1 : P.A2;
        const int kloc = (c < 4) ? c * BK : (c - 4) * BK;
        __syncthreads();  // WAR: prev iter's frag reads before restage
        #pragma unroll
        for (int j = 0; j < 2; ++j) {  // A: 512 16B units async
            int u = (wv * 2 + j) * 64 + l;
            int r = u >> 3, sg = (u & 7) ^ (r & 7);
            int gr = r0 + r; if (gr >= M) gr = M - 1;
            gl_lds16(Ap + (size_t)gr * HD + kloc + sg * 8, sA + (wv * 2 + j) * 1024);
        }
        #pragma unroll
        for (int j = 0; j < 8; ++j) {  // B: 2048 16B units async, WT is [256][512]
            int u = (wv * 8 + j) * 64 + l;
            int n = u >> 3, sg = (u & 7) ^ (n & 7);
            gl_lds16(P.WT + (size_t)n * 512 + c * BK + sg * 8, sB + (wv * 8 + j) * 1024);
        }
        __syncthreads();
        #pragma unroll
        for (int ks = 0; ks < 2; ++ks) {
            bf16x8 af[4], bfr[4];
            int sg = ks * 4 + lq;
            #pragma unroll
            for (int mt = 0; mt < 4; ++mt) {
                int m = mt * 16 + l15;
                af[mt] = *(const bf16x8*)(sA + m * 128 + ((sg ^ (m & 7)) << 4));
            }
            #pragma unroll
            for (int nt = 0; nt < 4; ++nt) {
                int n = wv * 64 + nt * 16 + l15;
                bfr[nt] = *(const bf16x8*)(sB + n * 128 + ((sg ^ (n & 7)) << 4));
            }
            #pragma unroll
            for (int mt = 0; mt < 4; ++mt)
                #pragma unroll
                for (int nt = 0; nt < 4; ++nt)
                    acc[mt][nt] = __builtin_amdgcn_mfma_f32_16x16x32_bf16(
                        af[mt], bfr[nt], acc[mt][nt], 0, 0, 0);
        }
    }
    #pragma unroll
    for (int nt = 0; nt < 4; ++nt) {
        int col = wv * 64 + nt * 16 + l15;
        float bs = P.bias[col];
        #pragma unroll
        for (int mt = 0; mt < 4; ++mt) {
            int rowb = r0 + mt * 16 + lq * 4;
            #pragma unroll
            for (int rg = 0; rg < 4; ++rg) {
                int row = rowb + rg;
                if (row < M)
                    P.out[(size_t)row * HD + col] = f2bf(gelu_f(acc[mt][nt][rg] + bs));
            }
        }
    }
}

// ---------------- head GEMM + LayerNorm epilogue, f32 out ----------------
struct LnArgs {
    const unsigned short* A; const unsigned short* WT; const float* bias;
    const float* g; const float* b2; float* out; int M;
};
__global__ __launch_bounds__(256, 3) void k_ln(LnArgs g0, LnArgs g1) {
    LnArgs P; if (blockIdx.y == 0) P = g0; else P = g1;
    const int Kt = HD;
    __shared__ char sm[BM * 128 + 256 * 128];
    char* sA = sm;
    char* sB = sm + BM * 128;
    const int t = threadIdx.x;
    const int wv = t >> 6, l = t & 63;
    const int l15 = l & 15, lq = l >> 4;
    const int r0 = blockIdx.x * BM;
    const int M = P.M;

    f32x4 acc[16];
    #pragma unroll
    for (int i = 0; i < 16; ++i) acc[i] = (f32x4){0, 0, 0, 0};

    #pragma unroll 1
    for (int c = 0; c < Kt / BK; ++c) {
        const int k0 = c * BK;
        __syncthreads();
        #pragma unroll
        for (int j = 0; j < 2; ++j) {  // A async
            int u = (wv * 2 + j) * 64 + l;
            int r = u >> 3, sg = (u & 7) ^ (r & 7);
            int gr = r0 + r; if (gr >= M) gr = M - 1;
            gl_lds16(P.A + (size_t)gr * Kt + k0 + sg * 8, sA + (wv * 2 + j) * 1024);
        }
        #pragma unroll
        for (int j = 0; j < 8; ++j) {  // B async, WT is [256][256]
            int u = (wv * 8 + j) * 64 + l;
            int n = u >> 3, sg = (u & 7) ^ (n & 7);
            gl_lds16(P.WT + (size_t)n * Kt + k0 + sg * 8, sB + (wv * 8 + j) * 1024);
        }
        __syncthreads();
        #pragma unroll
        for (int ks = 0; ks < 2; ++ks) {
            int sg = ks * 4 + lq;
            int m = wv * 16 + l15;
            bf16x8 af = *(const bf16x8*)(sA + m * 128 + ((sg ^ (m & 7)) << 4));
            #pragma unroll
            for (int nt = 0; nt < 16; ++nt) {
                int n = nt * 16 + l15;
                bf16x8 bfr = *(const bf16x8*)(sB + n * 128 + ((sg ^ (n & 7)) << 4));
                acc[nt] = __builtin_amdgcn_mfma_f32_16x16x32_bf16(af, bfr, acc[nt], 0, 0, 0);
            }
        }
    }
    #pragma unroll
    for (int nt = 0; nt < 16; ++nt) {
        float bs = P.bias[nt * 16 + l15];
        #pragma unroll
        for (int rg = 0; rg < 4; ++rg) acc[nt][rg] += bs;
    }
    float s0 = 0, s1 = 0, s2 = 0, s3 = 0;
    #pragma unroll
    for (int nt = 0; nt < 16; ++nt) { s0 += acc[nt][0]; s1 += acc[nt][1]; s2 += acc[nt][2]; s3 += acc[nt][3]; }
    #pragma unroll
    for (int off = 1; off < 16; off <<= 1) {
        s0 += __shfl_xor(s0, off, 64); s1 += __shfl_xor(s1, off, 64);
        s2 += __shfl_xor(s2, off, 64); s3 += __shfl_xor(s3, off, 64);
    }
    const float mu0 = s0 * (1.0f / HD), mu1 = s1 * (1.0f / HD),
                mu2 = s2 * (1.0f / HD), mu3 = s3 * (1.0f / HD);
    float q0 = 0, q1 = 0, q2 = 0, q3 = 0;
    #pragma unroll
    for (int nt = 0; nt < 16; ++nt) {
        float d0 = acc[nt][0] - mu0, d1 = acc[nt][1] - mu1,
              d2 = acc[nt][2] - mu2, d3 = acc[nt][3] - mu3;
        q0 += d0 * d0; q1 += d1 * d1; q2 += d2 * d2; q3 += d3 * d3;
    }
    #pragma unroll
    for (int off = 1; off < 16; off <<= 1) {
        q0 += __shfl_xor(q0, off, 64); q1 += __shfl_xor(q1, off, 64);
        q2 += __shfl_xor(q2, off, 64); q3 += __shfl_xor(q3, off, 64);
    }
    const float rs0 = rsqrtf(q0 * (1.0f / HD) + 1e-5f), rs1 = rsqrtf(q1 * (1.0f / HD) + 1e-5f),
                rs2 = rsqrtf(q2 * (1.0f / HD) + 1e-5f), rs3 = rsqrtf(q3 * (1.0f / HD) + 1e-5f);
    const int rowb = r0 + wv * 16 + lq * 4;
    #pragma unroll
    for (int nt = 0; nt < 16; ++nt) {
        int col = nt * 16 + l15;
        float gg = P.g[col], bb = P.b2[col];
        float mu[4] = {mu0, mu1, mu2, mu3};
        float rs[4] = {rs0, rs1, rs2, rs3};
        #pragma unroll
        for (int rg = 0; rg < 4; ++rg) {
            int row = rowb + rg;
            if (row < M)
                P.out[(size_t)row * HD + col] = (acc[nt][rg] - mu[rg]) * rs[rg] * gg + bb;
        }
    }
}

extern "C" void kernel_launch(void* const* d_in, const int* in_sizes, int n_in,
                              void* d_out, int out_size, void* d_ws, size_t ws_size,
                              hipStream_t stream) {
    const float* x_user     = (const float*)d_in[0];
    const float* x_item     = (const float*)d_in[1];
    const int*   ei_ui_src  = (const int*)d_in[2];
    const int*   ei_ui_dst  = (const int*)d_in[3];
    const int*   ei_iu_src  = (const int*)d_in[4];
    const int*   ei_iu_dst  = (const int*)d_in[5];
    const float* lin_user_W = (const float*)d_in[6];
    const float* lin_user_b = (const float*)d_in[7];
    const float* lin_item_W = (const float*)d_in[8];
    const float* lin_item_b = (const float*)d_in[9];
    const float* c0_ui_Wl = (const float*)d_in[10];
    const float* c0_ui_bl = (const float*)d_in[11];
    const float* c0_ui_Wr = (const float*)d_in[12];
    const float* c0_iu_Wl = (const float*)d_in[13];
    const float* c0_iu_bl = (const float*)d_in[14];
    const float* c0_iu_Wr = (const float*)d_in[15];
    const float* c1_ui_Wl = (const float*)d_in[16];
    const float* c1_ui_bl = (const float*)d_in[17];
    const float* c1_ui_Wr = (const float*)d_in[18];
    const float* c1_iu_Wl = (const float*)d_in[19];
    const float* c1_iu_bl = (const float*)d_in[20];
    const float* c1_iu_Wr = (const float*)d_in[21];
    const float* out_user_W = (const float*)d_in[22];
    const float* out_user_b = (const float*)d_in[23];
    const float* out_item_W = (const float*)d_in[24];
    const float* out_item_b = (const float*)d_in[25];
    const float* ln_user_g  = (const float*)d_in[26];
    const float* ln_user_b2 = (const float*)d_in[27];
    const float* ln_item_g  = (const float*)d_in[28];
    const float* ln_item_b2 = (const float*)d_in[29];

    char* ws = (char*)d_ws;
    size_t off = 0;
    auto alloc = [&](size_t bytes) -> void* {
        void* p = ws + off;
        off += (bytes + 255) & ~(size_t)255;
        return p;
    };
    typedef unsigned short u16;
    u16* hu_a = (u16*)alloc((size_t)NUSER * HD * 2);
    u16* hi_a = (u16*)alloc((size_t)NITEM * HD * 2);
    u16* aggI = (u16*)alloc((size_t)NITEM * HD * 2);   // mean msgs into items (ui)
    u16* aggU = (u16*)alloc((size_t)NUSER * HD * 2);   // mean msgs into users (iu)
    u16* WT_lu   = (u16*)alloc((size_t)HD * DIN * 2);
    u16* WT_li   = (u16*)alloc((size_t)HD * DIN * 2);
    u16* WT_c0ui = (u16*)alloc((size_t)HD * 2 * HD * 2);
    u16* WT_c0iu = (u16*)alloc((size_t)HD * 2 * HD * 2);
    u16* WT_c1ui = (u16*)alloc((size_t)HD * 2 * HD * 2);
    u16* WT_c1iu = (u16*)alloc((size_t)HD * 2 * HD * 2);
    u16* WT_ou   = (u16*)alloc((size_t)HD * HD * 2);
    u16* WT_oi   = (u16*)alloc((size_t)HD * HD * 2);
    int* rp_i  = (int*)alloc((NITEM + 1) * 4);
    int* rp_u  = (int*)alloc((NUSER + 1) * 4);
    int* cur_i = (int*)alloc(NITEM * 4);
    int* cur_u = (int*)alloc(NUSER * 4);
    int* cnt_i = (int*)alloc(NITEM * 4);
    int* cnt_u = (int*)alloc(NUSER * 4);
    int* sl_ui = (int*)alloc((size_t)NEDGE * 4);
    int* sl_iu = (int*)alloc((size_t)NEDGE * 4);
    int* csum_i = (int*)alloc(64 * 4);
    int* csum_u = (int*)alloc(64 * 4);

    // h pong buffers (bf16) live in d_out's 204.8MB; heads overwrite d_out last
    u16* hu_b = (u16*)d_out;
    u16* hi_b = (u16*)d_out + (size_t)NUSER * HD;

    const int MMG = (NUSER + BM - 1) / BM;
    const int NBI = (NITEM + SCHUNK - 1) / SCHUNK;
    const int NBU = (NUSER + SCHUNK - 1) / SCHUNK;

    // ---- CSR build ----
    hipMemsetAsync(cnt_i, 0, NITEM * 4, stream);
    hipMemsetAsync(cnt_u, 0, NUSER * 4, stream);
    k_hist2<<<dim3(1024, 2), 256, 0, stream>>>(ei_ui_dst, cnt_i, ei_iu_dst, cnt_u, NEDGE);
    k_scan_part<<<NBI + NBU, 1024, 0, stream>>>(cnt_i, rp_i, NITEM, NBI, csum_i,
                                                cnt_u, rp_u, NUSER, csum_u);
    k_scan_fin<<<NBI + NBU, 1024, 0, stream>>>(rp_i, cur_i, NITEM, NBI, csum_i,
                                               rp_u, cur_u, NUSER, NBU, csum_u);
    k_scatter2<<<dim3(1024, 2), 256, 0, stream>>>(ei_ui_src, ei_ui_dst, cur_i, sl_ui,
                                                  ei_iu_src, ei_iu_dst, cur_u, sl_iu, NEDGE);

    // ---- weight prep (single launch, 12 jobs) ----
    CvtT12 J;
    const float* srcs[12] = {lin_user_W, lin_item_W,
                             c0_ui_Wl, c0_ui_Wr, c0_iu_Wl, c0_iu_Wr,
                             c1_ui_Wl, c1_ui_Wr, c1_iu_Wl, c1_iu_Wr,
                             out_user_W, out_item_W};
    u16* dsts[12] = {WT_lu, WT_li, WT_c0ui, WT_c0ui, WT_c0iu, WT_c0iu,
                     WT_c1ui, WT_c1ui, WT_c1iu, WT_c1iu, WT_ou, WT_oi};
    int Ks[12]    = {DIN, DIN, HD, HD, HD, HD, HD, HD, HD, HD, HD, HD};
    int Kts[12]   = {DIN, DIN, 2*HD, 2*HD, 2*HD, 2*HD, 2*HD, 2*HD, 2*HD, 2*HD, HD, HD};
    int koffs[12] = {0, 0, 0, HD, 0, HD, 0, HD, 0, HD, 0, 0};
    for (int i = 0; i < 12; ++i) {
        J.src[i] = srcs[i]; J.dst[i] = dsts[i];
        J.K[i] = Ks[i]; J.Kt[i] = Kts[i]; J.koff[i] = koffs[i];
    }
    k_cvtT_all<<<dim3(128, 12), 256, 0, stream>>>(J);

    // ---- input projections (f32 A, one launch) ----
    ProjArgs pu = {x_user, WT_lu, lin_user_b, hu_a, NUSER};
    ProjArgs pi = {x_item, WT_li, lin_item_b, hi_a, NITEM};
    k_proj<<<dim3(MMG, 2), 256, 0, stream>>>(pu, pi);

    // ---- layer 0: both gathers in one launch, both conv GEMMs in one launch ----
    GatherArgs g0i = {hu_a, rp_i, sl_ui, aggI, NITEM};
    GatherArgs g0u = {hi_a, rp_u, sl_iu, aggU, NUSER};
    k_gather2<<<dim3(4096, 2), 256, 0, stream>>>(g0i, g0u);
    MmArgs m0i = {aggI, hi_a, WT_c0ui, c0_ui_bl, hi_b, NITEM};
    MmArgs m0u = {aggU, hu_a, WT_c0iu, c0_iu_bl, hu_b, NUSER};
    k_mm2<<<dim3(MMG, 2), 256, 0, stream>>>(m0i, m0u);

    // ---- layer 1 ----
    GatherArgs g1i = {hu_b, rp_i, sl_ui, aggI, NITEM};
    GatherArgs g1u = {hi_b, rp_u, sl_iu, aggU, NUSER};
    k_gather2<<<dim3(4096, 2), 256, 0, stream>>>(g1i, g1u);
    MmArgs m1i = {aggI, hi_b, WT_c1ui, c1_ui_bl, hi_a, NITEM};
    MmArgs m1u = {aggU, hu_b, WT_c1iu, c1_iu_bl, hu_a, NUSER};
    k_mm2<<<dim3(MMG, 2), 256, 0, stream>>>(m1i, m1u);

    // ---- heads + LayerNorm (one launch, read ws, write d_out) ----
    LnArgs hu = {hu_a, WT_ou, out_user_b, ln_user_g, ln_user_b2, (float*)d_out, NUSER};
    LnArgs hi = {hi_a, WT_oi, out_item_b, ln_item_g, ln_item_b2,
                 (float*)d_out + (size_t)NUSER * HD, NITEM};
    k_ln<<<dim3(MMG, 2), 256, 0, stream>>>(hu, hi);
}

// Round 8
// 1075.436 us; speedup vs baseline: 1.4792x; 1.1259x over previous
//
#include <hip/hip_runtime.h>
#include <math.h>

#define NUSER 100000
#define NITEM 100000
#define NEDGE 800000
#define DIN 128
#define HD 256
#define BM 64
#define BK 64

typedef __attribute__((ext_vector_type(8))) short bf16x8;
typedef __attribute__((ext_vector_type(4))) float f32x4;

__device__ __forceinline__ float gelu_f(float x) {
    return 0.5f * x * (1.0f + erff(x * 0.70710678118654752440f));
}
__device__ __forceinline__ unsigned short f2bf(float f) {
    union { unsigned int i; float f; } v; v.f = f;
    unsigned int r = (v.i + 0x7FFFu + ((v.i >> 16) & 1u)) >> 16;  // RNE
    return (unsigned short)r;
}
__device__ __forceinline__ float bflo(unsigned int p) {
    union { unsigned int i; float f; } v; v.i = p << 16; return v.f;
}
__device__ __forceinline__ float bfhi(unsigned int p) {
    union { unsigned int i; float f; } v; v.i = p & 0xFFFF0000u; return v.f;
}
// async global->LDS, 16B per lane; dest = lds base (wave-uniform) + lane*16
__device__ __forceinline__ void gl_lds16(const void* g, void* l) {
    __builtin_amdgcn_global_load_lds(
        (const __attribute__((address_space(1))) unsigned int*)g,
        (__attribute__((address_space(3))) unsigned int*)l, 16, 0, 0);
}

// ---------------- CSR build ----------------
__global__ void k_hist2(const int* __restrict__ dst0, int* __restrict__ cnt0,
                        const int* __restrict__ dst1, int* __restrict__ cnt1, int n) {
    const int* dst = blockIdx.y ? dst1 : dst0;
    int* cnt = blockIdx.y ? cnt1 : cnt0;
    for (int i = blockIdx.x * blockDim.x + threadIdx.x; i < n; i += gridDim.x * blockDim.x)
        atomicAdd(&cnt[dst[i]], 1);
}

#define SCHUNK 8192
__global__ __launch_bounds__(1024) void k_scan_part(
    const int* __restrict__ cnt0, int* __restrict__ rp0, int n0, int nb0, int* __restrict__ csum0,
    const int* __restrict__ cnt1, int* __restrict__ rp1, int n1, int* __restrict__ csum1) {
    const int b = blockIdx.x;
    const int* cnt; int* rp; int n; int* csum; int chunk;
    if (b < nb0) { cnt = cnt0; rp = rp0; n = n0; csum = csum0; chunk = b; }
    else         { cnt = cnt1; rp = rp1; n = n1; csum = csum1; chunk = b - nb0; }
    const int t = threadIdx.x;
    const int lane = t & 63, wid = t >> 6;
    const int base = chunk * SCHUNK + t * 8;

    int v[8]; int s = 0;
    #pragma unroll
    for (int k = 0; k < 8; ++k) {
        int idx = base + k;
        int x = (idx < n) ? cnt[idx] : 0;
        v[k] = s; s += x;
    }
    int ws = s;
    #pragma unroll
    for (int off = 1; off < 64; off <<= 1) {
        int y = __shfl_up(ws, off, 64);
        if (lane >= off) ws += y;
    }
    __shared__ int wsum[16];
    if (lane == 63) wsum[wid] = ws;
    __syncthreads();
    int wexc = 0;
    for (int w = 0; w < wid; ++w) wexc += wsum[w];
    const int texc = wexc + (ws - s);
    #pragma unroll
    for (int k = 0; k < 8; ++k) {
        int idx = base + k;
        if (idx < n) rp[idx] = texc + v[k];
    }
    if (t == 1023) csum[chunk] = texc + s;
}

__global__ __launch_bounds__(1024) void k_scan_fin(
    int* __restrict__ rp0, int* __restrict__ cur0, int n0, int nb0, const int* __restrict__ csum0,
    int* __restrict__ rp1, int* __restrict__ cur1, int n1, int nb1, const int* __restrict__ csum1) {
    const int b = blockIdx.x;
    int* rp; int* cur; int n; const int* csum; int chunk; int nb;
    if (b < nb0) { rp = rp0; cur = cur0; n = n0; csum = csum0; chunk = b;       nb = nb0; }
    else         { rp = rp1; cur = cur1; n = n1; csum = csum1; chunk = b - nb0; nb = nb1; }
    int off = 0;
    for (int w = 0; w < chunk; ++w) off += csum[w];
    const int t = threadIdx.x;
    const int base = chunk * SCHUNK + t;
    #pragma unroll
    for (int k = 0; k < 8; ++k) {
        int idx = base + k * 1024;
        if (idx < n) { int x = rp[idx] + off; rp[idx] = x; cur[idx] = x; }
    }
    if (chunk == nb - 1 && t == 0) rp[n] = off + csum[nb - 1];
}

__global__ void k_scatter2(const int* __restrict__ s0, const int* __restrict__ d0,
                           int* __restrict__ c0, int* __restrict__ l0,
                           const int* __restrict__ s1, const int* __restrict__ d1,
                           int* __restrict__ c1, int* __restrict__ l1, int n) {
    const int* src = blockIdx.y ? s1 : s0;
    const int* dst = blockIdx.y ? d1 : d0;
    int* cur = blockIdx.y ? c1 : c0;
    int* sl  = blockIdx.y ? l1 : l0;
    for (int i = blockIdx.x * blockDim.x + threadIdx.x; i < n; i += gridDim.x * blockDim.x) {
        int p = atomicAdd(&cur[dst[i]], 1);
        sl[p] = src[i];
    }
}

// ---------------- weight prep: all 12 transposed conversions in ONE launch ----------------
struct CvtT12 {
    const float* src[12];
    unsigned short* dst[12];
    int K[12]; int Kt[12]; int koff[12];
};
__global__ void k_cvtT_all(CvtT12 J) {
    const int job = blockIdx.y;
    const float* src = J.src[job];
    unsigned short* dst = J.dst[job];
    const int K = J.K[job], Kt = J.Kt[job], koff = J.koff[job];
    for (int i = blockIdx.x * blockDim.x + threadIdx.x; i < K * 256; i += gridDim.x * blockDim.x) {
        int k = i >> 8, n = i & 255;
        dst[(size_t)n * Kt + koff + k] = f2bf(src[i]);
    }
}

// ---------------- input projection: f32 A (convert during staging) + GELU, bf16 out ----------------
struct ProjArgs {
    const float* X; const unsigned short* WT; const float* bias;
    unsigned short* out; int M;
};
__global__ __launch_bounds__(256, 3) void k_proj(ProjArgs p0, ProjArgs p1) {
    ProjArgs P; if (blockIdx.y == 0) P = p0; else P = p1;
    const int Kt = DIN;
    __shared__ char sm[BM * 128 + 256 * 128];  // A 8KB + B 32KB; epilogue reuses 33KB
    char* sA = sm;
    char* sB = sm + BM * 128;
    const int t = threadIdx.x;
    const int wv = t >> 6, l = t & 63;
    const int l15 = l & 15, lq = l >> 4;
    const int r0 = blockIdx.x * BM;
    const int M = P.M;

    f32x4 acc[4][4];
    #pragma unroll
    for (int i = 0; i < 4; ++i)
        #pragma unroll
        for (int j = 0; j < 4; ++j) acc[i][j] = (f32x4){0, 0, 0, 0};

    #pragma unroll 1
    for (int c = 0; c < Kt / BK; ++c) {
        const int k0 = c * BK;
        __syncthreads();
        #pragma unroll
        for (int j = 0; j < 2; ++j) {  // A: 512 16B units, from f32 source (convert)
            int u = t + 256 * j;
            int r = u >> 3, sg = u & 7;
            int gr = r0 + r; if (gr >= M) gr = M - 1;
            const float* p = P.X + (size_t)gr * Kt + k0 + sg * 8;
            float4 f0 = *(const float4*)(p);
            float4 f1 = *(const float4*)(p + 4);
            uint4 v;
            v.x = (unsigned int)f2bf(f0.x) | ((unsigned int)f2bf(f0.y) << 16);
            v.y = (unsigned int)f2bf(f0.z) | ((unsigned int)f2bf(f0.w) << 16);
            v.z = (unsigned int)f2bf(f1.x) | ((unsigned int)f2bf(f1.y) << 16);
            v.w = (unsigned int)f2bf(f1.z) | ((unsigned int)f2bf(f1.w) << 16);
            *(uint4*)(sA + r * 128 + ((sg ^ (r & 7)) << 4)) = v;
        }
        #pragma unroll
        for (int j = 0; j < 8; ++j) {  // B: async, linear dest + inv-swizzled src
            int u = (wv * 8 + j) * 64 + l;
            int n = u >> 3, sg = (u & 7) ^ (n & 7);
            gl_lds16(P.WT + (size_t)n * Kt + k0 + sg * 8, sB + (wv * 8 + j) * 1024);
        }
        __syncthreads();
        #pragma unroll
        for (int ks = 0; ks < 2; ++ks) {
            bf16x8 af[4], bfr[4];
            int sg = ks * 4 + lq;
            #pragma unroll
            for (int mt = 0; mt < 4; ++mt) {
                int m = mt * 16 + l15;
                af[mt] = *(const bf16x8*)(sA + m * 128 + ((sg ^ (m & 7)) << 4));
            }
            #pragma unroll
            for (int nt = 0; nt < 4; ++nt) {
                int n = wv * 64 + nt * 16 + l15;
                bfr[nt] = *(const bf16x8*)(sB + n * 128 + ((sg ^ (n & 7)) << 4));
            }
            #pragma unroll
            for (int mt = 0; mt < 4; ++mt)
                #pragma unroll
                for (int nt = 0; nt < 4; ++nt)
                    acc[mt][nt] = __builtin_amdgcn_mfma_f32_16x16x32_bf16(
                        af[mt], bfr[nt], acc[mt][nt], 0, 0, 0);
        }
    }
    // epilogue: pack bf16 into LDS (stride 528), then coalesced uint4 stores
    __syncthreads();
    #pragma unroll
    for (int nt = 0; nt < 4; ++nt) {
        int col = wv * 64 + nt * 16 + l15;
        float bs = P.bias[col];
        #pragma unroll
        for (int mt = 0; mt < 4; ++mt) {
            int rowb = mt * 16 + lq * 4;
            #pragma unroll
            for (int rg = 0; rg < 4; ++rg)
                *(unsigned short*)(sm + (rowb + rg) * 528 + col * 2) =
                    f2bf(gelu_f(acc[mt][nt][rg] + bs));
        }
    }
    __syncthreads();
    #pragma unroll
    for (int j = 0; j < 8; ++j) {
        int u = t + 256 * j;
        int r = u >> 5, c = u & 31;
        int gr = r0 + r;
        if (gr < M) {
            uint4 v = *(const uint4*)(sm + r * 528 + c * 16);
            *(uint4*)((char*)P.out + (size_t)gr * 512 + c * 16) = v;
        }
    }
}

// ---------------- CSR mean gather (standalone, both relations in one launch) ----------------
struct GatherArgs {
    const unsigned short* h; const int* rp; const int* sl;
    unsigned short* agg; int nrows;
};
__global__ __launch_bounds__(256, 4) void k_gather2(GatherArgs g0, GatherArgs g1) {
    GatherArgs G; if (blockIdx.y == 0) G = g0; else G = g1;
    const int wv = threadIdx.x >> 6, l = threadIdx.x & 63;
    for (int row = blockIdx.x * 4 + wv; row < G.nrows; row += gridDim.x * 4) {
        int beg = G.rp[row], end = G.rp[row + 1];
        float a0 = 0, a1 = 0, a2 = 0, a3 = 0;
        int e = beg;
        #pragma unroll 1
        for (; e + 8 <= end; e += 8) {
            uint2 v0 = *(const uint2*)(G.h + (size_t)G.sl[e + 0] * HD + 4 * l);
            uint2 v1 = *(const uint2*)(G.h + (size_t)G.sl[e + 1] * HD + 4 * l);
            uint2 v2 = *(const uint2*)(G.h + (size_t)G.sl[e + 2] * HD + 4 * l);
            uint2 v3 = *(const uint2*)(G.h + (size_t)G.sl[e + 3] * HD + 4 * l);
            uint2 v4 = *(const uint2*)(G.h + (size_t)G.sl[e + 4] * HD + 4 * l);
            uint2 v5 = *(const uint2*)(G.h + (size_t)G.sl[e + 5] * HD + 4 * l);
            uint2 v6 = *(const uint2*)(G.h + (size_t)G.sl[e + 6] * HD + 4 * l);
            uint2 v7 = *(const uint2*)(G.h + (size_t)G.sl[e + 7] * HD + 4 * l);
            a0 += bflo(v0.x) + bflo(v1.x) + bflo(v2.x) + bflo(v3.x)
                + bflo(v4.x) + bflo(v5.x) + bflo(v6.x) + bflo(v7.x);
            a1 += bfhi(v0.x) + bfhi(v1.x) + bfhi(v2.x) + bfhi(v3.x)
                + bfhi(v4.x) + bfhi(v5.x) + bfhi(v6.x) + bfhi(v7.x);
            a2 += bflo(v0.y) + bflo(v1.y) + bflo(v2.y) + bflo(v3.y)
                + bflo(v4.y) + bflo(v5.y) + bflo(v6.y) + bflo(v7.y);
            a3 += bfhi(v0.y) + bfhi(v1.y) + bfhi(v2.y) + bfhi(v3.y)
                + bfhi(v4.y) + bfhi(v5.y) + bfhi(v6.y) + bfhi(v7.y);
        }
        #pragma unroll 1
        for (; e + 4 <= end; e += 4) {
            uint2 v0 = *(const uint2*)(G.h + (size_t)G.sl[e + 0] * HD + 4 * l);
            uint2 v1 = *(const uint2*)(G.h + (size_t)G.sl[e + 1] * HD + 4 * l);
            uint2 v2 = *(const uint2*)(G.h + (size_t)G.sl[e + 2] * HD + 4 * l);
            uint2 v3 = *(const uint2*)(G.h + (size_t)G.sl[e + 3] * HD + 4 * l);
            a0 += bflo(v0.x) + bflo(v1.x) + bflo(v2.x) + bflo(v3.x);
            a1 += bfhi(v0.x) + bfhi(v1.x) + bfhi(v2.x) + bfhi(v3.x);
            a2 += bflo(v0.y) + bflo(v1.y) + bflo(v2.y) + bflo(v3.y);
            a3 += bfhi(v0.y) + bfhi(v1.y) + bfhi(v2.y) + bfhi(v3.y);
        }
        #pragma unroll 1
        for (; e < end; ++e) {
            uint2 v = *(const uint2*)(G.h + (size_t)G.sl[e] * HD + 4 * l);
            a0 += bflo(v.x); a1 += bfhi(v.x); a2 += bflo(v.y); a3 += bfhi(v.y);
        }
        float inv = 1.0f / fmaxf((float)(end - beg), 1.0f);
        unsigned int lo = (unsigned int)f2bf(a0 * inv) | ((unsigned int)f2bf(a1 * inv) << 16);
        unsigned int hi = (unsigned int)f2bf(a2 * inv) | ((unsigned int)f2bf(a3 * inv) << 16);
        uint2 o = {lo, hi};
        *(uint2*)(G.agg + (size_t)row * HD + 4 * l) = o;
    }
}

// ---------------- conv GEMM (both relations): GELU([agg|h_dst] @ W + b) ----------------
// global_load_lds staging + LDS-repacked coalesced epilogue (fixes 2x write amp).
struct MmArgs {
    const unsigned short* A1; const unsigned short* A2;
    const unsigned short* WT; const float* bias;
    unsigned short* out; int M;
};
__global__ __launch_bounds__(256, 4) void k_mm2(MmArgs m0, MmArgs m1) {
    MmArgs P; if (blockIdx.y == 0) P = m0; else P = m1;
    __shared__ char sm[BM * 128 + 256 * 128];  // A 8KB + B 32KB; epilogue reuses 33KB
    char* sA = sm;
    char* sB = sm + BM * 128;
    const int t = threadIdx.x;
    const int wv = t >> 6, l = t & 63;
    const int l15 = l & 15, lq = l >> 4;
    const int r0 = blockIdx.x * BM;
    const int M = P.M;

    f32x4 acc[4][4];
    #pragma unroll
    for (int i = 0; i < 4; ++i)
        #pragma unroll
        for (int j = 0; j < 4; ++j) acc[i][j] = (f32x4){0, 0, 0, 0};

    #pragma unroll 1
    for (int c = 0; c < 8; ++c) {
        const unsigned short* Ap = (c < 4) ? P.A1 : P.A2;
        const int kloc = (c < 4) ? c * BK : (c - 4) * BK;
        __syncthreads();  // WAR: prev iter's frag reads before restage
        #pragma unroll
        for (int j = 0; j < 2; ++j) {  // A: 512 16B units async
            int u = (wv * 2 + j) * 64 + l;
            int r = u >> 3, sg = (u & 7) ^ (r & 7);
            int gr = r0 + r; if (gr >= M) gr = M - 1;
            gl_lds16(Ap + (size_t)gr * HD + kloc + sg * 8, sA + (wv * 2 + j) * 1024);
        }
        #pragma unroll
        for (int j = 0; j < 8; ++j) {  // B: 2048 16B units async, WT is [256][512]
            int u = (wv * 8 + j) * 64 + l;
            int n = u >> 3, sg = (u & 7) ^ (n & 7);
            gl_lds16(P.WT + (size_t)n * 512 + c * BK + sg * 8, sB + (wv * 8 + j) * 1024);
        }
        __syncthreads();
        #pragma unroll
        for (int ks = 0; ks < 2; ++ks) {
            bf16x8 af[4], bfr[4];
            int sg = ks * 4 + lq;
            #pragma unroll
            for (int mt = 0; mt < 4; ++mt) {
                int m = mt * 16 + l15;
                af[mt] = *(const bf16x8*)(sA + m * 128 + ((sg ^ (m & 7)) << 4));
            }
            #pragma unroll
            for (int nt = 0; nt < 4; ++nt) {
                int n = wv * 64 + nt * 16 + l15;
                bfr[nt] = *(const bf16x8*)(sB + n * 128 + ((sg ^ (n & 7)) << 4));
            }
            #pragma unroll
            for (int mt = 0; mt < 4; ++mt)
                #pragma unroll
                for (int nt = 0; nt < 4; ++nt)
                    acc[mt][nt] = __builtin_amdgcn_mfma_f32_16x16x32_bf16(
                        af[mt], bfr[nt], acc[mt][nt], 0, 0, 0);
        }
    }
    // epilogue: pack bf16 into LDS (stride 528), then coalesced uint4 stores
    __syncthreads();
    #pragma unroll
    for (int nt = 0; nt < 4; ++nt) {
        int col = wv * 64 + nt * 16 + l15;
        float bs = P.bias[col];
        #pragma unroll
        for (int mt = 0; mt < 4; ++mt) {
            int rowb = mt * 16 + lq * 4;
            #pragma unroll
            for (int rg = 0; rg < 4; ++rg)
                *(unsigned short*)(sm + (rowb + rg) * 528 + col * 2) =
                    f2bf(gelu_f(acc[mt][nt][rg] + bs));
        }
    }
    __syncthreads();
    #pragma unroll
    for (int j = 0; j < 8; ++j) {
        int u = t + 256 * j;
        int r = u >> 5, c = u & 31;
        int gr = r0 + r;
        if (gr < M) {
            uint4 v = *(const uint4*)(sm + r * 528 + c * 16);
            *(uint4*)((char*)P.out + (size_t)gr * 512 + c * 16) = v;
        }
    }
}

// ---------------- head GEMM + LayerNorm epilogue, f32 out ----------------
struct LnArgs {
    const unsigned short* A; const unsigned short* WT; const float* bias;
    const float* g; const float* b2; float* out; int M;
};
__global__ __launch_bounds__(256, 4) void k_ln(LnArgs g0, LnArgs g1) {
    LnArgs P; if (blockIdx.y == 0) P = g0; else P = g1;
    const int Kt = HD;
    __shared__ char sm[BM * 128 + 256 * 128];
    char* sA = sm;
    char* sB = sm + BM * 128;
    const int t = threadIdx.x;
    const int wv = t >> 6, l = t & 63;
    const int l15 = l & 15, lq = l >> 4;
    const int r0 = blockIdx.x * BM;
    const int M = P.M;

    f32x4 acc[16];
    #pragma unroll
    for (int i = 0; i < 16; ++i) acc[i] = (f32x4){0, 0, 0, 0};

    #pragma unroll 1
    for (int c = 0; c < Kt / BK; ++c) {
        const int k0 = c * BK;
        __syncthreads();
        #pragma unroll
        for (int j = 0; j < 2; ++j) {  // A async
            int u = (wv * 2 + j) * 64 + l;
            int r = u >> 3, sg = (u & 7) ^ (r & 7);
            int gr = r0 + r; if (gr >= M) gr = M - 1;
            gl_lds16(P.A + (size_t)gr * Kt + k0 + sg * 8, sA + (wv * 2 + j) * 1024);
        }
        #pragma unroll
        for (int j = 0; j < 8; ++j) {  // B async, WT is [256][256]
            int u = (wv * 8 + j) * 64 + l;
            int n = u >> 3, sg = (u & 7) ^ (n & 7);
            gl_lds16(P.WT + (size_t)n * Kt + k0 + sg * 8, sB + (wv * 8 + j) * 1024);
        }
        __syncthreads();
        #pragma unroll
        for (int ks = 0; ks < 2; ++ks) {
            int sg = ks * 4 + lq;
            int m = wv * 16 + l15;
            bf16x8 af = *(const bf16x8*)(sA + m * 128 + ((sg ^ (m & 7)) << 4));
            #pragma unroll
            for (int nt = 0; nt < 16; ++nt) {
                int n = nt * 16 + l15;
                bf16x8 bfr = *(const bf16x8*)(sB + n * 128 + ((sg ^ (n & 7)) << 4));
                acc[nt] = __builtin_amdgcn_mfma_f32_16x16x32_bf16(af, bfr, acc[nt], 0, 0, 0);
            }
        }
    }
    #pragma unroll
    for (int nt = 0; nt < 16; ++nt) {
        float bs = P.bias[nt * 16 + l15];
        #pragma unroll
        for (int rg = 0; rg < 4; ++rg) acc[nt][rg] += bs;
    }
    float s0 = 0, s1 = 0, s2 = 0, s3 = 0;
    #pragma unroll
    for (int nt = 0; nt < 16; ++nt) { s0 += acc[nt][0]; s1 += acc[nt][1]; s2 += acc[nt][2]; s3 += acc[nt][3]; }
    #pragma unroll
    for (int off = 1; off < 16; off <<= 1) {
        s0 += __shfl_xor(s0, off, 64); s1 += __shfl_xor(s1, off, 64);
        s2 += __shfl_xor(s2, off, 64); s3 += __shfl_xor(s3, off, 64);
    }
    const float mu0 = s0 * (1.0f / HD), mu1 = s1 * (1.0f / HD),
                mu2 = s2 * (1.0f / HD), mu3 = s3 * (1.0f / HD);
    float q0 = 0, q1 = 0, q2 = 0, q3 = 0;
    #pragma unroll
    for (int nt = 0; nt < 16; ++nt) {
        float d0 = acc[nt][0] - mu0, d1 = acc[nt][1] - mu1,
              d2 = acc[nt][2] - mu2, d3 = acc[nt][3] - mu3;
        q0 += d0 * d0; q1 += d1 * d1; q2 += d2 * d2; q3 += d3 * d3;
    }
    #pragma unroll
    for (int off = 1; off < 16; off <<= 1) {
        q0 += __shfl_xor(q0, off, 64); q1 += __shfl_xor(q1, off, 64);
        q2 += __shfl_xor(q2, off, 64); q3 += __shfl_xor(q3, off, 64);
    }
    const float rs0 = rsqrtf(q0 * (1.0f / HD) + 1e-5f), rs1 = rsqrtf(q1 * (1.0f / HD) + 1e-5f),
                rs2 = rsqrtf(q2 * (1.0f / HD) + 1e-5f), rs3 = rsqrtf(q3 * (1.0f / HD) + 1e-5f);
    const int rowb = r0 + wv * 16 + lq * 4;
    #pragma unroll
    for (int nt = 0; nt < 16; ++nt) {
        int col = nt * 16 + l15;
        float gg = P.g[col], bb = P.b2[col];
        float mu[4] = {mu0, mu1, mu2, mu3};
        float rs[4] = {rs0, rs1, rs2, rs3};
        #pragma unroll
        for (int rg = 0; rg < 4; ++rg) {
            int row = rowb + rg;
            if (row < M)
                P.out[(size_t)row * HD + col] = (acc[nt][rg] - mu[rg]) * rs[rg] * gg + bb;
        }
    }
}

extern "C" void kernel_launch(void* const* d_in, const int* in_sizes, int n_in,
                              void* d_out, int out_size, void* d_ws, size_t ws_size,
                              hipStream_t stream) {
    const float* x_user     = (const float*)d_in[0];
    const float* x_item     = (const float*)d_in[1];
    const int*   ei_ui_src  = (const int*)d_in[2];
    const int*   ei_ui_dst  = (const int*)d_in[3];
    const int*   ei_iu_src  = (const int*)d_in[4];
    const int*   ei_iu_dst  = (const int*)d_in[5];
    const float* lin_user_W = (const float*)d_in[6];
    const float* lin_user_b = (const float*)d_in[7];
    const float* lin_item_W = (const float*)d_in[8];
    const float* lin_item_b = (const float*)d_in[9];
    const float* c0_ui_Wl = (const float*)d_in[10];
    const float* c0_ui_bl = (const float*)d_in[11];
    const float* c0_ui_Wr = (const float*)d_in[12];
    const float* c0_iu_Wl = (const float*)d_in[13];
    const float* c0_iu_bl = (const float*)d_in[14];
    const float* c0_iu_Wr = (const float*)d_in[15];
    const float* c1_ui_Wl = (const float*)d_in[16];
    const float* c1_ui_bl = (const float*)d_in[17];
    const float* c1_ui_Wr = (const float*)d_in[18];
    const float* c1_iu_Wl = (const float*)d_in[19];
    const float* c1_iu_bl = (const float*)d_in[20];
    const float* c1_iu_Wr = (const float*)d_in[21];
    const float* out_user_W = (const float*)d_in[22];
    const float* out_user_b = (const float*)d_in[23];
    const float* out_item_W = (const float*)d_in[24];
    const float* out_item_b = (const float*)d_in[25];
    const float* ln_user_g  = (const float*)d_in[26];
    const float* ln_user_b2 = (const float*)d_in[27];
    const float* ln_item_g  = (const float*)d_in[28];
    const float* ln_item_b2 = (const float*)d_in[29];

    char* ws = (char*)d_ws;
    size_t off = 0;
    auto alloc = [&](size_t bytes) -> void* {
        void* p = ws + off;
        off += (bytes + 255) & ~(size_t)255;
        return p;
    };
    typedef unsigned short u16;
    u16* hu_a = (u16*)alloc((size_t)NUSER * HD * 2);
    u16* hi_a = (u16*)alloc((size_t)NITEM * HD * 2);
    u16* aggI = (u16*)alloc((size_t)NITEM * HD * 2);   // mean msgs into items (ui)
    u16* aggU = (u16*)alloc((size_t)NUSER * HD * 2);   // mean msgs into users (iu)
    u16* WT_lu   = (u16*)alloc((size_t)HD * DIN * 2);
    u16* WT_li   = (u16*)alloc((size_t)HD * DIN * 2);
    u16* WT_c0ui = (u16*)alloc((size_t)HD * 2 * HD * 2);
    u16* WT_c0iu = (u16*)alloc((size_t)HD * 2 * HD * 2);
    u16* WT_c1ui = (u16*)alloc((size_t)HD * 2 * HD * 2);
    u16* WT_c1iu = (u16*)alloc((size_t)HD * 2 * HD * 2);
    u16* WT_ou   = (u16*)alloc((size_t)HD * HD * 2);
    u16* WT_oi   = (u16*)alloc((size_t)HD * HD * 2);
    int* rp_i  = (int*)alloc((NITEM + 1) * 4);
    int* rp_u  = (int*)alloc((NUSER + 1) * 4);
    int* cur_i = (int*)alloc(NITEM * 4);
    int* cur_u = (int*)alloc(NUSER * 4);
    int* cnt_i = (int*)alloc(NITEM * 4);
    int* cnt_u = (int*)alloc(NUSER * 4);
    int* sl_ui = (int*)alloc((size_t)NEDGE * 4);
    int* sl_iu = (int*)alloc((size_t)NEDGE * 4);
    int* csum_i = (int*)alloc(64 * 4);
    int* csum_u = (int*)alloc(64 * 4);

    // h pong buffers (bf16) live in d_out's 204.8MB; heads overwrite d_out last
    u16* hu_b = (u16*)d_out;
    u16* hi_b = (u16*)d_out + (size_t)NUSER * HD;

    const int MMG = (NUSER + BM - 1) / BM;
    const int NBI = (NITEM + SCHUNK - 1) / SCHUNK;
    const int NBU = (NUSER + SCHUNK - 1) / SCHUNK;

    // ---- CSR build ----
    hipMemsetAsync(cnt_i, 0, NITEM * 4, stream);
    hipMemsetAsync(cnt_u, 0, NUSER * 4, stream);
    k_hist2<<<dim3(1024, 2), 256, 0, stream>>>(ei_ui_dst, cnt_i, ei_iu_dst, cnt_u, NEDGE);
    k_scan_part<<<NBI + NBU, 1024, 0, stream>>>(cnt_i, rp_i, NITEM, NBI, csum_i,
                                                cnt_u, rp_u, NUSER, csum_u);
    k_scan_fin<<<NBI + NBU, 1024, 0, stream>>>(rp_i, cur_i, NITEM, NBI, csum_i,
                                               rp_u, cur_u, NUSER, NBU, csum_u);
    k_scatter2<<<dim3(1024, 2), 256, 0, stream>>>(ei_ui_src, ei_ui_dst, cur_i, sl_ui,
                                                  ei_iu_src, ei_iu_dst, cur_u, sl_iu, NEDGE);

    // ---- weight prep (single launch, 12 jobs) ----
    CvtT12 J;
    const float* srcs[12] = {lin_user_W, lin_item_W,
                             c0_ui_Wl, c0_ui_Wr, c0_iu_Wl, c0_iu_Wr,
                             c1_ui_Wl, c1_ui_Wr, c1_iu_Wl, c1_iu_Wr,
                             out_user_W, out_item_W};
    u16* dsts[12] = {WT_lu, WT_li, WT_c0ui, WT_c0ui, WT_c0iu, WT_c0iu,
                     WT_c1ui, WT_c1ui, WT_c1iu, WT_c1iu, WT_ou, WT_oi};
    int Ks[12]    = {DIN, DIN, HD, HD, HD, HD, HD, HD, HD, HD, HD, HD};
    int Kts[12]   = {DIN, DIN, 2*HD, 2*HD, 2*HD, 2*HD, 2*HD, 2*HD, 2*HD, 2*HD, HD, HD};
    int koffs[12] = {0, 0, 0, HD, 0, HD, 0, HD, 0, HD, 0, 0};
    for (int i = 0; i < 12; ++i) {
        J.src[i] = srcs[i]; J.dst[i] = dsts[i];
        J.K[i] = Ks[i]; J.Kt[i] = Kts[i]; J.koff[i] = koffs[i];
    }
    k_cvtT_all<<<dim3(128, 12), 256, 0, stream>>>(J);

    // ---- input projections (f32 A, one launch) ----
    ProjArgs pu = {x_user, WT_lu, lin_user_b, hu_a, NUSER};
    ProjArgs pi = {x_item, WT_li, lin_item_b, hi_a, NITEM};
    k_proj<<<dim3(MMG, 2), 256, 0, stream>>>(pu, pi);

    // ---- layer 0: both gathers in one launch, both conv GEMMs in one launch ----
    GatherArgs g0i = {hu_a, rp_i, sl_ui, aggI, NITEM};
    GatherArgs g0u = {hi_a, rp_u, sl_iu, aggU, NUSER};
    k_gather2<<<dim3(4096, 2), 256, 0, stream>>>(g0i, g0u);
    MmArgs m0i = {aggI, hi_a, WT_c0ui, c0_ui_bl, hi_b, NITEM};
    MmArgs m0u = {aggU, hu_a, WT_c0iu, c0_iu_bl, hu_b, NUSER};
    k_mm2<<<dim3(MMG, 2), 256, 0, stream>>>(m0i, m0u);

    // ---- layer 1 ----
    GatherArgs g1i = {hu_b, rp_i, sl_ui, aggI, NITEM};
    GatherArgs g1u = {hi_b, rp_u, sl_iu, aggU, NUSER};
    k_gather2<<<dim3(4096, 2), 256, 0, stream>>>(g1i, g1u);
    MmArgs m1i = {aggI, hi_b, WT_c1ui, c1_ui_bl, hi_a, NITEM};
    MmArgs m1u = {aggU, hu_b, WT_c1iu, c1_iu_bl, hu_a, NUSER};
    k_mm2<<<dim3(MMG, 2), 256, 0, stream>>>(m1i, m1u);

    // ---- heads + LayerNorm (one launch, read ws, write d_out) ----
    LnArgs hu = {hu_a, WT_ou, out_user_b, ln_user_g, ln_user_b2, (float*)d_out, NUSER};
    LnArgs hi = {hi_a, WT_oi, out_item_b, ln_item_g, ln_item_b2,
                 (float*)d_out + (size_t)NUSER * HD, NITEM};
    k_ln<<<dim3(MMG, 2), 256, 0, stream>>>(hu, hi);
}

// Round 9
// 1024.660 us; speedup vs baseline: 1.5525x; 1.0496x over previous
//
#include <hip/hip_runtime.h>
#include <math.h>

#define NUSER 100000
#define NITEM 100000
#define NEDGE 800000
#define DIN 128
#define HD 256
#define BM 64
#define BK 64

typedef __attribute__((ext_vector_type(8))) short bf16x8;
typedef __attribute__((ext_vector_type(4))) float f32x4;

__device__ __forceinline__ float gelu_f(float x) {
    return 0.5f * x * (1.0f + erff(x * 0.70710678118654752440f));
}
__device__ __forceinline__ unsigned short f2bf(float f) {
    union { unsigned int i; float f; } v; v.f = f;
    unsigned int r = (v.i + 0x7FFFu + ((v.i >> 16) & 1u)) >> 16;  // RNE
    return (unsigned short)r;
}
__device__ __forceinline__ float bflo(unsigned int p) {
    union { unsigned int i; float f; } v; v.i = p << 16; return v.f;
}
__device__ __forceinline__ float bfhi(unsigned int p) {
    union { unsigned int i; float f; } v; v.i = p & 0xFFFF0000u; return v.f;
}
// async global->LDS, 16B per lane; dest = lds base (wave-uniform) + lane*16
__device__ __forceinline__ void gl_lds16(const void* g, void* l) {
    __builtin_amdgcn_global_load_lds(
        (const __attribute__((address_space(1))) unsigned int*)g,
        (__attribute__((address_space(3))) unsigned int*)l, 16, 0, 0);
}

// ---------------- scan (unchanged) ----------------
#define SCHUNK 8192
__global__ __launch_bounds__(1024) void k_scan_part(
    const int* __restrict__ cnt0, int* __restrict__ rp0, int n0, int nb0, int* __restrict__ csum0,
    const int* __restrict__ cnt1, int* __restrict__ rp1, int n1, int* __restrict__ csum1) {
    const int b = blockIdx.x;
    const int* cnt; int* rp; int n; int* csum; int chunk;
    if (b < nb0) { cnt = cnt0; rp = rp0; n = n0; csum = csum0; chunk = b; }
    else         { cnt = cnt1; rp = rp1; n = n1; csum = csum1; chunk = b - nb0; }
    const int t = threadIdx.x;
    const int lane = t & 63, wid = t >> 6;
    const int base = chunk * SCHUNK + t * 8;

    int v[8]; int s = 0;
    #pragma unroll
    for (int k = 0; k < 8; ++k) {
        int idx = base + k;
        int x = (idx < n) ? cnt[idx] : 0;
        v[k] = s; s += x;
    }
    int ws = s;
    #pragma unroll
    for (int off = 1; off < 64; off <<= 1) {
        int y = __shfl_up(ws, off, 64);
        if (lane >= off) ws += y;
    }
    __shared__ int wsum[16];
    if (lane == 63) wsum[wid] = ws;
    __syncthreads();
    int wexc = 0;
    for (int w = 0; w < wid; ++w) wexc += wsum[w];
    const int texc = wexc + (ws - s);
    #pragma unroll
    for (int k = 0; k < 8; ++k) {
        int idx = base + k;
        if (idx < n) rp[idx] = texc + v[k];
    }
    if (t == 1023) csum[chunk] = texc + s;
}

__global__ __launch_bounds__(1024) void k_scan_fin(
    int* __restrict__ rp0, int* __restrict__ cur0, int n0, int nb0, const int* __restrict__ csum0,
    int* __restrict__ rp1, int* __restrict__ cur1, int n1, int nb1, const int* __restrict__ csum1) {
    const int b = blockIdx.x;
    int* rp; int* cur; int n; const int* csum; int chunk; int nb;
    if (b < nb0) { rp = rp0; cur = cur0; n = n0; csum = csum0; chunk = b;       nb = nb0; }
    else         { rp = rp1; cur = cur1; n = n1; csum = csum1; chunk = b - nb0; nb = nb1; }
    int off = 0;
    for (int w = 0; w < chunk; ++w) off += csum[w];
    const int t = threadIdx.x;
    const int base = chunk * SCHUNK + t;
    #pragma unroll
    for (int k = 0; k < 8; ++k) {
        int idx = base + k * 1024;
        if (idx < n) { int x = rp[idx] + off; rp[idx] = x; cur[idx] = x; }
    }
    if (chunk == nb - 1 && t == 0) rp[n] = off + csum[nb - 1];
}

// ---------------- fused prep: 12 cvtT jobs + 2 hist jobs in one launch ----------------
// blockIdx.x (fastest dispatch dim) selects the job -> types interleave across CUs.
struct CvtT12 {
    const float* src[12];
    unsigned short* dst[12];
    int K[12]; int Kt[12]; int koff[12];
};
__global__ void k_prep(CvtT12 J, const int* __restrict__ hd0, int* __restrict__ hc0,
                       const int* __restrict__ hd1, int* __restrict__ hc1, int nE) {
    const int x = blockIdx.x;
    const int stride = gridDim.y * blockDim.x;
    const int i0 = blockIdx.y * blockDim.x + threadIdx.x;
    if (x < 12) {
        const float* src = J.src[x];
        unsigned short* dst = J.dst[x];
        const int K = J.K[x], Kt = J.Kt[x], koff = J.koff[x];
        for (int i = i0; i < K * 256; i += stride) {
            int k = i >> 8, n = i & 255;
            dst[(size_t)n * Kt + koff + k] = f2bf(src[i]);
        }
    } else {
        const int* dst = (x == 12) ? hd0 : hd1;
        int* cnt = (x == 12) ? hc0 : hc1;
        for (int i = i0; i < nE; i += stride)
            atomicAdd(&cnt[dst[i]], 1);
    }
}

// ---------------- fused: input projections (x=0,1) + CSR scatter (x=2,3) ----------------
// Scatter's random-RMW latency hides under proj's MFMA work on the same CUs.
struct ProjArgs {
    const float* X; const unsigned short* WT; const float* bias;
    unsigned short* out; int M;
};
struct ScArgs { const int* src; const int* dst; int* cur; int* sl; };
__global__ __launch_bounds__(256, 3) void k_proj_sc(ProjArgs p0, ProjArgs p1,
                                                    ScArgs s0, ScArgs s1, int nE) {
    const int ty = blockIdx.x;
    if (ty >= 2) {  // scatter
        ScArgs S = (ty == 2) ? s0 : s1;
        const int stride = gridDim.y * blockDim.x;
        for (int i = blockIdx.y * blockDim.x + threadIdx.x; i < nE; i += stride) {
            int p = atomicAdd(&S.cur[S.dst[i]], 1);
            S.sl[p] = S.src[i];
        }
        return;
    }
    ProjArgs P = (ty == 0) ? p0 : p1;
    const int Kt = DIN;
    __shared__ char sm[BM * 128 + 256 * 128];  // A 8KB + B 32KB; epilogue reuses 33KB
    char* sA = sm;
    char* sB = sm + BM * 128;
    const int t = threadIdx.x;
    const int wv = t >> 6, l = t & 63;
    const int l15 = l & 15, lq = l >> 4;
    const int r0 = blockIdx.y * BM;
    const int M = P.M;

    f32x4 acc[4][4];
    #pragma unroll
    for (int i = 0; i < 4; ++i)
        #pragma unroll
        for (int j = 0; j < 4; ++j) acc[i][j] = (f32x4){0, 0, 0, 0};

    #pragma unroll 1
    for (int c = 0; c < Kt / BK; ++c) {
        const int k0 = c * BK;
        __syncthreads();
        #pragma unroll
        for (int j = 0; j < 2; ++j) {  // A: 512 16B units, from f32 source (convert)
            int u = t + 256 * j;
            int r = u >> 3, sg = u & 7;
            int gr = r0 + r; if (gr >= M) gr = M - 1;
            const float* p = P.X + (size_t)gr * Kt + k0 + sg * 8;
            float4 f0 = *(const float4*)(p);
            float4 f1 = *(const float4*)(p + 4);
            uint4 v;
            v.x = (unsigned int)f2bf(f0.x) | ((unsigned int)f2bf(f0.y) << 16);
            v.y = (unsigned int)f2bf(f0.z) | ((unsigned int)f2bf(f0.w) << 16);
            v.z = (unsigned int)f2bf(f1.x) | ((unsigned int)f2bf(f1.y) << 16);
            v.w = (unsigned int)f2bf(f1.z) | ((unsigned int)f2bf(f1.w) << 16);
            *(uint4*)(sA + r * 128 + ((sg ^ (r & 7)) << 4)) = v;
        }
        #pragma unroll
        for (int j = 0; j < 8; ++j) {  // B: async, linear dest + inv-swizzled src
            int u = (wv * 8 + j) * 64 + l;
            int n = u >> 3, sg = (u & 7) ^ (n & 7);
            gl_lds16(P.WT + (size_t)n * Kt + k0 + sg * 8, sB + (wv * 8 + j) * 1024);
        }
        __syncthreads();
        #pragma unroll
        for (int ks = 0; ks < 2; ++ks) {
            bf16x8 af[4], bfr[4];
            int sg = ks * 4 + lq;
            #pragma unroll
            for (int mt = 0; mt < 4; ++mt) {
                int m = mt * 16 + l15;
                af[mt] = *(const bf16x8*)(sA + m * 128 + ((sg ^ (m & 7)) << 4));
            }
            #pragma unroll
            for (int nt = 0; nt < 4; ++nt) {
                int n = wv * 64 + nt * 16 + l15;
                bfr[nt] = *(const bf16x8*)(sB + n * 128 + ((sg ^ (n & 7)) << 4));
            }
            #pragma unroll
            for (int mt = 0; mt < 4; ++mt)
                #pragma unroll
                for (int nt = 0; nt < 4; ++nt)
                    acc[mt][nt] = __builtin_amdgcn_mfma_f32_16x16x32_bf16(
                        af[mt], bfr[nt], acc[mt][nt], 0, 0, 0);
        }
    }
    // epilogue: pack bf16 into LDS (stride 528), then coalesced uint4 stores
    __syncthreads();
    #pragma unroll
    for (int nt = 0; nt < 4; ++nt) {
        int col = wv * 64 + nt * 16 + l15;
        float bs = P.bias[col];
        #pragma unroll
        for (int mt = 0; mt < 4; ++mt) {
            int rowb = mt * 16 + lq * 4;
            #pragma unroll
            for (int rg = 0; rg < 4; ++rg)
                *(unsigned short*)(sm + (rowb + rg) * 528 + col * 2) =
                    f2bf(gelu_f(acc[mt][nt][rg] + bs));
        }
    }
    __syncthreads();
    #pragma unroll
    for (int j = 0; j < 8; ++j) {
        int u = t + 256 * j;
        int r = u >> 5, c = u & 31;
        int gr = r0 + r;
        if (gr < M) {
            uint4 v = *(const uint4*)(sm + r * 528 + c * 16);
            *(uint4*)((char*)P.out + (size_t)gr * 512 + c * 16) = v;
        }
    }
}

// ---------------- CSR mean gather (standalone, both relations in one launch) ----------------
struct GatherArgs {
    const unsigned short* h; const int* rp; const int* sl;
    unsigned short* agg; int nrows;
};
__global__ __launch_bounds__(256, 4) void k_gather2(GatherArgs g0, GatherArgs g1) {
    GatherArgs G; if (blockIdx.y == 0) G = g0; else G = g1;
    const int wv = threadIdx.x >> 6, l = threadIdx.x & 63;
    for (int row = blockIdx.x * 4 + wv; row < G.nrows; row += gridDim.x * 4) {
        int beg = G.rp[row], end = G.rp[row + 1];
        float a0 = 0, a1 = 0, a2 = 0, a3 = 0;
        int e = beg;
        #pragma unroll 1
        for (; e + 8 <= end; e += 8) {
            uint2 v0 = *(const uint2*)(G.h + (size_t)G.sl[e + 0] * HD + 4 * l);
            uint2 v1 = *(const uint2*)(G.h + (size_t)G.sl[e + 1] * HD + 4 * l);
            uint2 v2 = *(const uint2*)(G.h + (size_t)G.sl[e + 2] * HD + 4 * l);
            uint2 v3 = *(const uint2*)(G.h + (size_t)G.sl[e + 3] * HD + 4 * l);
            uint2 v4 = *(const uint2*)(G.h + (size_t)G.sl[e + 4] * HD + 4 * l);
            uint2 v5 = *(const uint2*)(G.h + (size_t)G.sl[e + 5] * HD + 4 * l);
            uint2 v6 = *(const uint2*)(G.h + (size_t)G.sl[e + 6] * HD + 4 * l);
            uint2 v7 = *(const uint2*)(G.h + (size_t)G.sl[e + 7] * HD + 4 * l);
            a0 += bflo(v0.x) + bflo(v1.x) + bflo(v2.x) + bflo(v3.x)
                + bflo(v4.x) + bflo(v5.x) + bflo(v6.x) + bflo(v7.x);
            a1 += bfhi(v0.x) + bfhi(v1.x) + bfhi(v2.x) + bfhi(v3.x)
                + bfhi(v4.x) + bfhi(v5.x) + bfhi(v6.x) + bfhi(v7.x);
            a2 += bflo(v0.y) + bflo(v1.y) + bflo(v2.y) + bflo(v3.y)
                + bflo(v4.y) + bflo(v5.y) + bflo(v6.y) + bflo(v7.y);
            a3 += bfhi(v0.y) + bfhi(v1.y) + bfhi(v2.y) + bfhi(v3.y)
                + bfhi(v4.y) + bfhi(v5.y) + bfhi(v6.y) + bfhi(v7.y);
        }
        #pragma unroll 1
        for (; e + 4 <= end; e += 4) {
            uint2 v0 = *(const uint2*)(G.h + (size_t)G.sl[e + 0] * HD + 4 * l);
            uint2 v1 = *(const uint2*)(G.h + (size_t)G.sl[e + 1] * HD + 4 * l);
            uint2 v2 = *(const uint2*)(G.h + (size_t)G.sl[e + 2] * HD + 4 * l);
            uint2 v3 = *(const uint2*)(G.h + (size_t)G.sl[e + 3] * HD + 4 * l);
            a0 += bflo(v0.x) + bflo(v1.x) + bflo(v2.x) + bflo(v3.x);
            a1 += bfhi(v0.x) + bfhi(v1.x) + bfhi(v2.x) + bfhi(v3.x);
            a2 += bflo(v0.y) + bflo(v1.y) + bflo(v2.y) + bflo(v3.y);
            a3 += bfhi(v0.y) + bfhi(v1.y) + bfhi(v2.y) + bfhi(v3.y);
        }
        #pragma unroll 1
        for (; e < end; ++e) {
            uint2 v = *(const uint2*)(G.h + (size_t)G.sl[e] * HD + 4 * l);
            a0 += bflo(v.x); a1 += bfhi(v.x); a2 += bflo(v.y); a3 += bfhi(v.y);
        }
        float inv = 1.0f / fmaxf((float)(end - beg), 1.0f);
        unsigned int lo = (unsigned int)f2bf(a0 * inv) | ((unsigned int)f2bf(a1 * inv) << 16);
        unsigned int hi = (unsigned int)f2bf(a2 * inv) | ((unsigned int)f2bf(a3 * inv) << 16);
        uint2 o = {lo, hi};
        *(uint2*)(G.agg + (size_t)row * HD + 4 * l) = o;
    }
}

// ---------------- conv GEMM (both relations): GELU([agg|h_dst] @ W + b) ----------------
struct MmArgs {
    const unsigned short* A1; const unsigned short* A2;
    const unsigned short* WT; const float* bias;
    unsigned short* out; int M;
};
__global__ __launch_bounds__(256, 4) void k_mm2(MmArgs m0, MmArgs m1) {
    MmArgs P; if (blockIdx.y == 0) P = m0; else P = m1;
    __shared__ char sm[BM * 128 + 256 * 128];  // A 8KB + B 32KB; epilogue reuses 33KB
    char* sA = sm;
    char* sB = sm + BM * 128;
    const int t = threadIdx.x;
    const int wv = t >> 6, l = t & 63;
    const int l15 = l & 15, lq = l >> 4;
    const int r0 = blockIdx.x * BM;
    const int M = P.M;

    f32x4 acc[4][4];
    #pragma unroll
    for (int i = 0; i < 4; ++i)
        #pragma unroll
        for (int j = 0; j < 4; ++j) acc[i][j] = (f32x4){0, 0, 0, 0};

    #pragma unroll 1
    for (int c = 0; c < 8; ++c) {
        const unsigned short* Ap = (c < 4) ? P.A1 : P.A2;
        const int kloc = (c < 4) ? c * BK : (c - 4) * BK;
        __syncthreads();  // WAR: prev iter's frag reads before restage
        #pragma unroll
        for (int j = 0; j < 2; ++j) {  // A: 512 16B units async
            int u = (wv * 2 + j) * 64 + l;
            int r = u >> 3, sg = (u & 7) ^ (r & 7);
            int gr = r0 + r; if (gr >= M) gr = M - 1;
            gl_lds16(Ap + (size_t)gr * HD + kloc + sg * 8, sA + (wv * 2 + j) * 1024);
        }
        #pragma unroll
        for (int j = 0; j < 8; ++j) {  // B: 2048 16B units async, WT is [256][512]
            int u = (wv * 8 + j) * 64 + l;
            int n = u >> 3, sg = (u & 7) ^ (n & 7);
            gl_lds16(P.WT + (size_t)n * 512 + c * BK + sg * 8, sB + (wv * 8 + j) * 1024);
        }
        __syncthreads();
        #pragma unroll
        for (int ks = 0; ks < 2; ++ks) {
            bf16x8 af[4], bfr[4];
            int sg = ks * 4 + lq;
            #pragma unroll
            for (int mt = 0; mt < 4; ++mt) {
                int m = mt * 16 + l15;
                af[mt] = *(const bf16x8*)(sA + m * 128 + ((sg ^ (m & 7)) << 4));
            }
            #pragma unroll
            for (int nt = 0; nt < 4; ++nt) {
                int n = wv * 64 + nt * 16 + l15;
                bfr[nt] = *(const bf16x8*)(sB + n * 128 + ((sg ^ (n & 7)) << 4));
            }
            #pragma unroll
            for (int mt = 0; mt < 4; ++mt)
                #pragma unroll
                for (int nt = 0; nt < 4; ++nt)
                    acc[mt][nt] = __builtin_amdgcn_mfma_f32_16x16x32_bf16(
                        af[mt], bfr[nt], acc[mt][nt], 0, 0, 0);
        }
    }
    // epilogue: pack bf16 into LDS (stride 528), then coalesced uint4 stores
    __syncthreads();
    #pragma unroll
    for (int nt = 0; nt < 4; ++nt) {
        int col = wv * 64 + nt * 16 + l15;
        float bs = P.bias[col];
        #pragma unroll
        for (int mt = 0; mt < 4; ++mt) {
            int rowb = mt * 16 + lq * 4;
            #pragma unroll
            for (int rg = 0; rg < 4; ++rg)
                *(unsigned short*)(sm + (rowb + rg) * 528 + col * 2) =
                    f2bf(gelu_f(acc[mt][nt][rg] + bs));
        }
    }
    __syncthreads();
    #pragma unroll
    for (int j = 0; j < 8; ++j) {
        int u = t + 256 * j;
        int r = u >> 5, c = u & 31;
        int gr = r0 + r;
        if (gr < M) {
            uint4 v = *(const uint4*)(sm + r * 528 + c * 16);
            *(uint4*)((char*)P.out + (size_t)gr * 512 + c * 16) = v;
        }
    }
}

// ---------------- head GEMM + LayerNorm epilogue, f32 out ----------------
struct LnArgs {
    const unsigned short* A; const unsigned short* WT; const float* bias;
    const float* g; const float* b2; float* out; int M;
};
__global__ __launch_bounds__(256, 4) void k_ln(LnArgs g0, LnArgs g1) {
    LnArgs P; if (blockIdx.y == 0) P = g0; else P = g1;
    const int Kt = HD;
    __shared__ char sm[BM * 128 + 256 * 128];
    char* sA = sm;
    char* sB = sm + BM * 128;
    const int t = threadIdx.x;
    const int wv = t >> 6, l = t & 63;
    const int l15 = l & 15, lq = l >> 4;
    const int r0 = blockIdx.x * BM;
    const int M = P.M;

    f32x4 acc[16];
    #pragma unroll
    for (int i = 0; i < 16; ++i) acc[i] = (f32x4){0, 0, 0, 0};

    #pragma unroll 1
    for (int c = 0; c < Kt / BK; ++c) {
        const int k0 = c * BK;
        __syncthreads();
        #pragma unroll
        for (int j = 0; j < 2; ++j) {  // A async
            int u = (wv * 2 + j) * 64 + l;
            int r = u >> 3, sg = (u & 7) ^ (r & 7);
            int gr = r0 + r; if (gr >= M) gr = M - 1;
            gl_lds16(P.A + (size_t)gr * Kt + k0 + sg * 8, sA + (wv * 2 + j) * 1024);
        }
        #pragma unroll
        for (int j = 0; j < 8; ++j) {  // B async, WT is [256][256]
            int u = (wv * 8 + j) * 64 + l;
            int n = u >> 3, sg = (u & 7) ^ (n & 7);
            gl_lds16(P.WT + (size_t)n * Kt + k0 + sg * 8, sB + (wv * 8 + j) * 1024);
        }
        __syncthreads();
        #pragma unroll
        for (int ks = 0; ks < 2; ++ks) {
            int sg = ks * 4 + lq;
            int m = wv * 16 + l15;
            bf16x8 af = *(const bf16x8*)(sA + m * 128 + ((sg ^ (m & 7)) << 4));
            #pragma unroll
            for (int nt = 0; nt < 16; ++nt) {
                int n = nt * 16 + l15;
                bf16x8 bfr = *(const bf16x8*)(sB + n * 128 + ((sg ^ (n & 7)) << 4));
                acc[nt] = __builtin_amdgcn_mfma_f32_16x16x32_bf16(af, bfr, acc[nt], 0, 0, 0);
            }
        }
    }
    #pragma unroll
    for (int nt = 0; nt < 16; ++nt) {
        float bs = P.bias[nt * 16 + l15];
        #pragma unroll
        for (int rg = 0; rg < 4; ++rg) acc[nt][rg] += bs;
    }
    float s0 = 0, s1 = 0, s2 = 0, s3 = 0;
    #pragma unroll
    for (int nt = 0; nt < 16; ++nt) { s0 += acc[nt][0]; s1 += acc[nt][1]; s2 += acc[nt][2]; s3 += acc[nt][3]; }
    #pragma unroll
    for (int off = 1; off < 16; off <<= 1) {
        s0 += __shfl_xor(s0, off, 64); s1 += __shfl_xor(s1, off, 64);
        s2 += __shfl_xor(s2, off, 64); s3 += __shfl_xor(s3, off, 64);
    }
    const float mu0 = s0 * (1.0f / HD), mu1 = s1 * (1.0f / HD),
                mu2 = s2 * (1.0f / HD), mu3 = s3 * (1.0f / HD);
    float q0 = 0, q1 = 0, q2 = 0, q3 = 0;
    #pragma unroll
    for (int nt = 0; nt < 16; ++nt) {
        float d0 = acc[nt][0] - mu0, d1 = acc[nt][1] - mu1,
              d2 = acc[nt][2] - mu2, d3 = acc[nt][3] - mu3;
        q0 += d0 * d0; q1 += d1 * d1; q2 += d2 * d2; q3 += d3 * d3;
    }
    #pragma unroll
    for (int off = 1; off < 16; off <<= 1) {
        q0 += __shfl_xor(q0, off, 64); q1 += __shfl_xor(q1, off, 64);
        q2 += __shfl_xor(q2, off, 64); q3 += __shfl_xor(q3, off, 64);
    }
    const float rs0 = rsqrtf(q0 * (1.0f / HD) + 1e-5f), rs1 = rsqrtf(q1 * (1.0f / HD) + 1e-5f),
                rs2 = rsqrtf(q2 * (1.0f / HD) + 1e-5f), rs3 = rsqrtf(q3 * (1.0f / HD) + 1e-5f);
    const int rowb = r0 + wv * 16 + lq * 4;
    #pragma unroll
    for (int nt = 0; nt < 16; ++nt) {
        int col = nt * 16 + l15;
        float gg = P.g[col], bb = P.b2[col];
        float mu[4] = {mu0, mu1, mu2, mu3};
        float rs[4] = {rs0, rs1, rs2, rs3};
        #pragma unroll
        for (int rg = 0; rg < 4; ++rg) {
            int row = rowb + rg;
            if (row < M)
                P.out[(size_t)row * HD + col] = (acc[nt][rg] - mu[rg]) * rs[rg] * gg + bb;
        }
    }
}

extern "C" void kernel_launch(void* const* d_in, const int* in_sizes, int n_in,
                              void* d_out, int out_size, void* d_ws, size_t ws_size,
                              hipStream_t stream) {
    const float* x_user     = (const float*)d_in[0];
    const float* x_item     = (const float*)d_in[1];
    const int*   ei_ui_src  = (const int*)d_in[2];
    const int*   ei_ui_dst  = (const int*)d_in[3];
    const int*   ei_iu_src  = (const int*)d_in[4];
    const int*   ei_iu_dst  = (const int*)d_in[5];
    const float* lin_user_W = (const float*)d_in[6];
    const float* lin_user_b = (const float*)d_in[7];
    const float* lin_item_W = (const float*)d_in[8];
    const float* lin_item_b = (const float*)d_in[9];
    const float* c0_ui_Wl = (const float*)d_in[10];
    const float* c0_ui_bl = (const float*)d_in[11];
    const float* c0_ui_Wr = (const float*)d_in[12];
    const float* c0_iu_Wl = (const float*)d_in[13];
    const float* c0_iu_bl = (const float*)d_in[14];
    const float* c0_iu_Wr = (const float*)d_in[15];
    const float* c1_ui_Wl = (const float*)d_in[16];
    const float* c1_ui_bl = (const float*)d_in[17];
    const float* c1_ui_Wr = (const float*)d_in[18];
    const float* c1_iu_Wl = (const float*)d_in[19];
    const float* c1_iu_bl = (const float*)d_in[20];
    const float* c1_iu_Wr = (const float*)d_in[21];
    const float* out_user_W = (const float*)d_in[22];
    const float* out_user_b = (const float*)d_in[23];
    const float* out_item_W = (const float*)d_in[24];
    const float* out_item_b = (const float*)d_in[25];
    const float* ln_user_g  = (const float*)d_in[26];
    const float* ln_user_b2 = (const float*)d_in[27];
    const float* ln_item_g  = (const float*)d_in[28];
    const float* ln_item_b2 = (const float*)d_in[29];

    char* ws = (char*)d_ws;
    size_t off = 0;
    auto alloc = [&](size_t bytes) -> void* {
        void* p = ws + off;
        off += (bytes + 255) & ~(size_t)255;
        return p;
    };
    typedef unsigned short u16;
    u16* hu_a = (u16*)alloc((size_t)NUSER * HD * 2);
    u16* hi_a = (u16*)alloc((size_t)NITEM * HD * 2);
    u16* aggI = (u16*)alloc((size_t)NITEM * HD * 2);   // mean msgs into items (ui)
    u16* aggU = (u16*)alloc((size_t)NUSER * HD * 2);   // mean msgs into users (iu)
    u16* WT_lu   = (u16*)alloc((size_t)HD * DIN * 2);
    u16* WT_li   = (u16*)alloc((size_t)HD * DIN * 2);
    u16* WT_c0ui = (u16*)alloc((size_t)HD * 2 * HD * 2);
    u16* WT_c0iu = (u16*)alloc((size_t)HD * 2 * HD * 2);
    u16* WT_c1ui = (u16*)alloc((size_t)HD * 2 * HD * 2);
    u16* WT_c1iu = (u16*)alloc((size_t)HD * 2 * HD * 2);
    u16* WT_ou   = (u16*)alloc((size_t)HD * HD * 2);
    u16* WT_oi   = (u16*)alloc((size_t)HD * HD * 2);
    int* rp_i  = (int*)alloc((NITEM + 1) * 4);
    int* rp_u  = (int*)alloc((NUSER + 1) * 4);
    int* cur_i = (int*)alloc(NITEM * 4);
    int* cur_u = (int*)alloc(NUSER * 4);
    int* cnt_i = (int*)alloc(NITEM * 4);
    int* cnt_u = (int*)alloc(NUSER * 4);
    int* sl_ui = (int*)alloc((size_t)NEDGE * 4);
    int* sl_iu = (int*)alloc((size_t)NEDGE * 4);
    int* csum_i = (int*)alloc(64 * 4);
    int* csum_u = (int*)alloc(64 * 4);

    // h pong buffers (bf16) live in d_out's 204.8MB; heads overwrite d_out last
    u16* hu_b = (u16*)d_out;
    u16* hi_b = (u16*)d_out + (size_t)NUSER * HD;

    const int MMG = (NUSER + BM - 1) / BM;
    const int NBI = (NITEM + SCHUNK - 1) / SCHUNK;
    const int NBU = (NUSER + SCHUNK - 1) / SCHUNK;

    // ---- prep: hist (x=12,13) + 12 cvtT jobs (x=0..11), one launch ----
    hipMemsetAsync(cnt_i, 0, NITEM * 4, stream);
    hipMemsetAsync(cnt_u, 0, NUSER * 4, stream);
    CvtT12 J;
    const float* srcs[12] = {lin_user_W, lin_item_W,
                             c0_ui_Wl, c0_ui_Wr, c0_iu_Wl, c0_iu_Wr,
                             c1_ui_Wl, c1_ui_Wr, c1_iu_Wl, c1_iu_Wr,
                             out_user_W, out_item_W};
    u16* dsts[12] = {WT_lu, WT_li, WT_c0ui, WT_c0ui, WT_c0iu, WT_c0iu,
                     WT_c1ui, WT_c1ui, WT_c1iu, WT_c1iu, WT_ou, WT_oi};
    int Ks[12]    = {DIN, DIN, HD, HD, HD, HD, HD, HD, HD, HD, HD, HD};
    int Kts[12]   = {DIN, DIN, 2*HD, 2*HD, 2*HD, 2*HD, 2*HD, 2*HD, 2*HD, 2*HD, HD, HD};
    int koffs[12] = {0, 0, 0, HD, 0, HD, 0, HD, 0, HD, 0, 0};
    for (int i = 0; i < 12; ++i) {
        J.src[i] = srcs[i]; J.dst[i] = dsts[i];
        J.K[i] = Ks[i]; J.Kt[i] = Kts[i]; J.koff[i] = koffs[i];
    }
    k_prep<<<dim3(14, 192), 256, 0, stream>>>(J, ei_ui_dst, cnt_i, ei_iu_dst, cnt_u, NEDGE);

    // ---- scan ----
    k_scan_part<<<NBI + NBU, 1024, 0, stream>>>(cnt_i, rp_i, NITEM, NBI, csum_i,
                                                cnt_u, rp_u, NUSER, csum_u);
    k_scan_fin<<<NBI + NBU, 1024, 0, stream>>>(rp_i, cur_i, NITEM, NBI, csum_i,
                                               rp_u, cur_u, NUSER, NBU, csum_u);

    // ---- projections (x=0,1) + scatters (x=2,3), one launch ----
    ProjArgs pu = {x_user, WT_lu, lin_user_b, hu_a, NUSER};
    ProjArgs pi = {x_item, WT_li, lin_item_b, hi_a, NITEM};
    ScArgs su = {ei_ui_src, ei_ui_dst, cur_i, sl_ui};
    ScArgs si = {ei_iu_src, ei_iu_dst, cur_u, sl_iu};
    k_proj_sc<<<dim3(4, MMG), 256, 0, stream>>>(pu, pi, su, si, NEDGE);

    // ---- layer 0: both gathers in one launch, both conv GEMMs in one launch ----
    GatherArgs g0i = {hu_a, rp_i, sl_ui, aggI, NITEM};
    GatherArgs g0u = {hi_a, rp_u, sl_iu, aggU, NUSER};
    k_gather2<<<dim3(4096, 2), 256, 0, stream>>>(g0i, g0u);
    MmArgs m0i = {aggI, hi_a, WT_c0ui, c0_ui_bl, hi_b, NITEM};
    MmArgs m0u = {aggU, hu_a, WT_c0iu, c0_iu_bl, hu_b, NUSER};
    k_mm2<<<dim3(MMG, 2), 256, 0, stream>>>(m0i, m0u);

    // ---- layer 1 ----
    GatherArgs g1i = {hu_b, rp_i, sl_ui, aggI, NITEM};
    GatherArgs g1u = {hi_b, rp_u, sl_iu, aggU, NUSER};
    k_gather2<<<dim3(4096, 2), 256, 0, stream>>>(g1i, g1u);
    MmArgs m1i = {aggI, hi_b, WT_c1ui, c1_ui_bl, hi_a, NITEM};
    MmArgs m1u = {aggU, hu_b, WT_c1iu, c1_iu_bl, hu_a, NUSER};
    k_mm2<<<dim3(MMG, 2), 256, 0, stream>>>(m1i, m1u);

    // ---- heads + LayerNorm (one launch, read ws, write d_out) ----
    LnArgs hu = {hu_a, WT_ou, out_user_b, ln_user_g, ln_user_b2, (float*)d_out, NUSER};
    LnArgs hi = {hi_a, WT_oi, out_item_b, ln_item_g, ln_item_b2,
                 (float*)d_out + (size_t)NUSER * HD, NITEM};
    k_ln<<<dim3(MMG, 2), 256, 0, stream>>>(hu, hi);
}